// Round 1
// baseline (18965.933 us; speedup 1.0000x reference)
//
#include <hip/hip_runtime.h>

#define T_STEPS 3
#define NB 2
#define H_LO 360
#define W_LO 640
#define H_HI 720
#define W_HI 1280
#define HW_LO (H_LO*W_LO)
#define HW_HI (H_HI*W_HI)
#define TILE 12

__device__ __forceinline__ int imin(int a,int b){return a<b?a:b;}
__device__ __forceinline__ int imax(int a,int b){return a>b?a:b;}
__device__ __forceinline__ int iclamp(int v,int lo,int hi){return imin(imax(v,lo),hi);}

__device__ __forceinline__ float depth_tx(float d0){
  float d = 10.0f / (100.0f - d0*99.9f);
  return (d - 0.1f) / 99.9f;
}

__device__ __forceinline__ void cubw(float t, float* w){
  const float a = -0.75f;
  float t2 = t*t, t3 = t2*t;
  w[0] = a*(t3 - 2.0f*t2 + t);
  w[1] = (a+2.0f)*t3 - (a+3.0f)*t2 + 1.0f;
  float s = 1.0f - t;
  w[2] = (a+2.0f)*s*s*s - (a+3.0f)*s*s + 1.0f;
  float u = 2.0f - t;
  w[3] = a*u*u*u - 5.0f*a*u*u + 8.0f*a*u - 4.0f*a;
}

// ---------------- FB = bicubic jitter-aligned upsample of [frame, depth_tx] ----------------
__global__ __launch_bounds__(256) void k_prep(const float* __restrict__ frame,
    const float* __restrict__ depth, const float* __restrict__ jit,
    float* __restrict__ FB){
  int idx = blockIdx.x*256 + threadIdx.x;
  if (idx >= NB*HW_HI) return;
  int n = idx / HW_HI, p = idx - n*HW_HI;
  int y = p / W_HI, x = p - y*W_HI;
  float jx = jit[n*2], jy = jit[n*2+1];
  float gx = (2.0f*(float)x + 1.0f)/(float)W_HI - 1.0f + 2.0f*(0.5f - jx)/(float)W_LO;
  float gy = (2.0f*(float)y + 1.0f)/(float)H_HI - 1.0f + 2.0f*(0.5f - jy)/(float)H_LO;
  float ix = ((gx + 1.0f)*(float)W_LO - 1.0f)*0.5f;
  float iy = ((gy + 1.0f)*(float)H_LO - 1.0f)*0.5f;
  float xf = floorf(ix), yf = floorf(iy);
  float tx = ix - xf, ty = iy - yf;
  int xi = (int)xf, yi = (int)yf;
  float wx[4], wy[4]; cubw(tx, wx); cubw(ty, wy);
  int xs[4], ys[4];
  #pragma unroll
  for (int j=0;j<4;j++){ xs[j]=iclamp(xi-1+j,0,W_LO-1); ys[j]=iclamp(yi-1+j,0,H_LO-1); }
  const float* fb = frame + n*3*HW_LO;
  const float* db = depth + n*HW_LO;
  float a0=0.f,a1=0.f,a2=0.f,a3=0.f;
  #pragma unroll
  for (int i=0;i<4;i++){
    #pragma unroll
    for (int j=0;j<4;j++){
      float wgt = wy[i]*wx[j];
      int off = ys[i]*W_LO + xs[j];
      a0 += wgt*fb[off];
      a1 += wgt*fb[HW_LO+off];
      a2 += wgt*fb[2*HW_LO+off];
      a3 += wgt*depth_tx(db[off]);
    }
  }
  float* o = FB + n*4*HW_HI + p;
  o[0] = a0; o[HW_HI] = a1; o[2*HW_HI] = a2; o[3*HW_HI] = a3;
}

// ---------------- histB = bicubic warp of histA by bilinearly-upsampled mv; OOB -> FB ----------------
__global__ __launch_bounds__(256) void k_warp(const float* __restrict__ histA,
    const float* __restrict__ mv, const float* __restrict__ FB,
    float* __restrict__ histB){
  int idx = blockIdx.x*256 + threadIdx.x;
  if (idx >= NB*HW_HI) return;
  int n = idx / HW_HI, p = idx - n*HW_HI;
  int y = p / W_HI, x = p - y*W_HI;
  float cy = fmaxf(((float)y + 0.5f)/2.0f - 0.5f, 0.0f);
  float cx = fmaxf(((float)x + 0.5f)/2.0f - 0.5f, 0.0f);
  float y0f = floorf(cy), x0f = floorf(cx);
  float tyv = cy - y0f, txv = cx - x0f;
  int y0 = iclamp((int)y0f, 0, H_LO-1), y1 = iclamp((int)y0f+1, 0, H_LO-1);
  int x0 = iclamp((int)x0f, 0, W_LO-1), x1 = iclamp((int)x0f+1, 0, W_LO-1);
  const float* mb = mv + n*HW_LO*2;
  float gx, gy;
  {
    float v00 = mb[(y0*W_LO+x0)*2], v01 = mb[(y0*W_LO+x1)*2];
    float v10 = mb[(y1*W_LO+x0)*2], v11 = mb[(y1*W_LO+x1)*2];
    float r0 = v00*(1.0f-tyv) + v10*tyv;
    float r1 = v01*(1.0f-tyv) + v11*tyv;
    gx = r0*(1.0f-txv) + r1*txv;
  }
  {
    float v00 = mb[(y0*W_LO+x0)*2+1], v01 = mb[(y0*W_LO+x1)*2+1];
    float v10 = mb[(y1*W_LO+x0)*2+1], v11 = mb[(y1*W_LO+x1)*2+1];
    float r0 = v00*(1.0f-tyv) + v10*tyv;
    float r1 = v01*(1.0f-tyv) + v11*tyv;
    gy = r0*(1.0f-txv) + r1*txv;
  }
  bool oob = (gx > 1.0f) || (gx < -1.0f) || (gy > 1.0f) || (gy < -1.0f);
  const float* hb = histA + n*4*HW_HI;
  float* ob = histB + n*4*HW_HI + p;
  if (oob) {
    const float* f = FB + n*4*HW_HI + p;
    #pragma unroll
    for (int c=0;c<4;c++) ob[c*HW_HI] = f[c*HW_HI];
  } else {
    float ix = ((gx + 1.0f)*(float)W_HI - 1.0f)*0.5f;
    float iy = ((gy + 1.0f)*(float)H_HI - 1.0f)*0.5f;
    float xf = floorf(ix), yf = floorf(iy);
    float tx = ix - xf, ty = iy - yf;
    int xi = (int)xf, yi = (int)yf;
    float wx[4], wy[4]; cubw(tx, wx); cubw(ty, wy);
    int xs[4], ys[4];
    #pragma unroll
    for (int j=0;j<4;j++){ xs[j]=iclamp(xi-1+j,0,W_HI-1); ys[j]=iclamp(yi-1+j,0,H_HI-1); }
    float a0=0.f,a1=0.f,a2=0.f,a3=0.f;
    #pragma unroll
    for (int i=0;i<4;i++){
      #pragma unroll
      for (int j=0;j<4;j++){
        float wgt = wy[i]*wx[j];
        int off = ys[i]*W_HI + xs[j];
        a0 += wgt*hb[off];
        a1 += wgt*hb[HW_HI+off];
        a2 += wgt*hb[2*HW_HI+off];
        a3 += wgt*hb[3*HW_HI+off];
      }
    }
    ob[0] = a0; ob[HW_HI] = a1; ob[2*HW_HI] = a2; ob[3*HW_HI] = a3;
  }
}

// ---------------- fused conv1+conv2+conv3 + blend, one 12x12 output tile per block ----------------
// LDS: s_h1 [64][16][16] (64KB), s_h2 [64][14][14] (49KB, doubles as w1 staging),
//      s_buf [4608] (18KB: cnn_in 8x18x18 then w2 8-ic chunks). Total 134144 B.
__global__ __launch_bounds__(256) void k_fused(
    const float* __restrict__ frame, const float* __restrict__ depth,
    const float* __restrict__ jit, const float* __restrict__ histIn,
    const float* __restrict__ FB,
    const float* __restrict__ w1g, const float* __restrict__ b1g,
    const float* __restrict__ w2g, const float* __restrict__ b2g,
    const float* __restrict__ w3g, const float* __restrict__ b3g,
    float* __restrict__ histOut, float* __restrict__ outp)
{
  __shared__ __align__(16) float s_h1[64*256];
  __shared__ __align__(16) float s_h2[64*196];
  __shared__ __align__(16) float s_buf[4608];
  float* s_w1 = s_h2;  // w1 (4608) + b1 (64) live here during stages A/B

  const int tid = threadIdx.x;
  const int n  = blockIdx.z;
  const int r0 = blockIdx.y * TILE;
  const int c0 = blockIdx.x * TILE;
  const float jx = jit[n*2], jy = jit[n*2+1];
  const int jix = (int)floorf(jx*2.0f), jiy = (int)floorf(jy*2.0f);
  const float* fbase = frame + n*3*HW_LO;
  const float* dbase = depth + n*HW_LO;
  const float* hbase = histIn + n*4*HW_HI;

  // ---- Stage A: cnn_in tile (8 x 18 x 18) + w1/b1 staging ----
  for (int e = tid; e < 2592; e += 256) {
    int ic = e / 324; int r = e - ic*324; int ty = r / 18; int tx = r - ty*18;
    int cgy = iclamp(r0 - 3 + ty, 0, H_HI-1);
    int cgx = iclamp(c0 - 3 + tx, 0, W_HI-1);
    float v = 0.0f;
    if (ic < 4) {  // frame_up on the fly (zero-upsample + integer jitter shift)
      int yy = cgy - jiy, xx = cgx - jix;
      if (yy >= 0 && xx >= 0 && (yy & 1) == 0 && (xx & 1) == 0) {
        int ysrc = yy >> 1, xsrc = xx >> 1;
        v = (ic < 3) ? fbase[ic*HW_LO + ysrc*W_LO + xsrc]
                     : depth_tx(dbase[ysrc*W_LO + xsrc]);
      }
    } else {
      v = hbase[(ic-4)*HW_HI + cgy*W_HI + cgx];
    }
    s_buf[e] = v;
  }
  for (int e = tid; e < 4672; e += 256) {
    if (e < 4608) {  // relayout w1 [oc][ic][tap] -> [ic][tap][oc]
      int oc = e & 63; int tap = (e >> 6) % 9; int ic = e / 576;
      s_w1[e] = w1g[(oc*8 + ic)*9 + tap];
    } else {
      s_w1[e] = b1g[e - 4608];
    }
  }
  __syncthreads();

  const int p2 = tid >> 2;   // pixel group: pixels p2 + 64k
  const int og = tid & 3;    // oc group: channels og*16 .. og*16+15

  // ---- Stage B: h1 = relu(conv1(cnn_in)) over 16x16 ----
  {
    int rowB[4][3], colB[4][3];
    #pragma unroll
    for (int k=0;k<4;k++){
      int p = p2 + 64*k; int ty = p >> 4, tx = p & 15;
      int cgy = iclamp(r0-2+ty, 0, H_HI-1);
      int cgx = iclamp(c0-2+tx, 0, W_HI-1);
      #pragma unroll
      for (int d=0;d<3;d++){
        rowB[k][d] = iclamp(cgy+d-1, 0, H_HI-1) - (r0-3);
        colB[k][d] = iclamp(cgx+d-1, 0, W_HI-1) - (c0-3);
      }
    }
    float acc[4][16];
    #pragma unroll
    for (int k=0;k<4;k++)
      #pragma unroll
      for (int j=0;j<16;j++) acc[k][j] = s_w1[4608 + og*16 + j];
    for (int ic=0; ic<8; ic++){
      #pragma unroll
      for (int ky=0;ky<3;ky++){
        #pragma unroll
        for (int kx=0;kx<3;kx++){
          const float* wp = &s_w1[(ic*9 + ky*3 + kx)*64 + og*16];
          float wv[16];
          #pragma unroll
          for (int j=0;j<16;j++) wv[j] = wp[j];
          #pragma unroll
          for (int k=0;k<4;k++){
            float v = s_buf[ic*324 + rowB[k][ky]*18 + colB[k][kx]];
            #pragma unroll
            for (int j=0;j<16;j++) acc[k][j] += wv[j]*v;
          }
        }
      }
    }
    #pragma unroll
    for (int k=0;k<4;k++){
      int p = p2 + 64*k;
      #pragma unroll
      for (int j=0;j<16;j++)
        s_h1[(og*16+j)*256 + p] = fmaxf(acc[k][j], 0.0f);
    }
  }
  __syncthreads();

  // ---- Stage C: h2 = relu(conv2(h1)) over 14x14, w2 staged 8 input-channels at a time ----
  int rowC[4][3], colC[4][3], pcv[4]; bool pval[4];
  #pragma unroll
  for (int k=0;k<4;k++){
    int p = p2 + 64*k;
    pval[k] = (p < 196);
    int pc = imin(p, 195);
    pcv[k] = pc;
    int ty = pc / 14, tx = pc - ty*14;
    int cgy = iclamp(r0-1+ty, 0, H_HI-1);
    int cgx = iclamp(c0-1+tx, 0, W_HI-1);
    #pragma unroll
    for (int d=0;d<3;d++){
      rowC[k][d] = iclamp(cgy+d-1, 0, H_HI-1) - (r0-2);
      colC[k][d] = iclamp(cgx+d-1, 0, W_HI-1) - (c0-2);
    }
  }
  float acc2[4][16];
  #pragma unroll
  for (int k=0;k<4;k++)
    #pragma unroll
    for (int j=0;j<16;j++) acc2[k][j] = b2g[og*16+j];
  for (int icb=0; icb<8; icb++){
    __syncthreads();
    for (int e = tid; e < 4608; e += 256){  // w2 chunk -> [ic8][tap][oc]
      int oc = e & 63; int tap = (e >> 6) % 9; int ic8 = e / 576;
      s_buf[e] = w2g[(oc*64 + icb*8 + ic8)*9 + tap];
    }
    __syncthreads();
    for (int ic8=0; ic8<8; ic8++){
      int icg = icb*8 + ic8;
      #pragma unroll
      for (int ky=0;ky<3;ky++){
        #pragma unroll
        for (int kx=0;kx<3;kx++){
          const float* wp = &s_buf[(ic8*9 + ky*3 + kx)*64 + og*16];
          float wv[16];
          #pragma unroll
          for (int j=0;j<16;j++) wv[j] = wp[j];
          #pragma unroll
          for (int k=0;k<4;k++){
            float v = s_h1[icg*256 + rowC[k][ky]*16 + colC[k][kx]];
            #pragma unroll
            for (int j=0;j<16;j++) acc2[k][j] += wv[j]*v;
          }
        }
      }
    }
  }
  __syncthreads();
  #pragma unroll
  for (int k=0;k<4;k++){
    if (pval[k]) {
      #pragma unroll
      for (int j=0;j<16;j++)
        s_h2[(og*16+j)*196 + pcv[k]] = fmaxf(acc2[k][j], 0.0f);
    }
  }
  __syncthreads();

  // ---- Stage D: conv3 (64->2) + blend + outputs over 12x12 ----
  if (tid < 144) {
    int ty = tid / 12, tx = tid - ty*12;
    int gy = r0 + ty, gx = c0 + tx;
    if (gy < H_HI && gx < W_HI) {
      float a0 = b3g[0], a1 = b3g[1];
      int rr[3], cc[3];
      #pragma unroll
      for (int d=0;d<3;d++){
        rr[d] = iclamp(gy+d-1, 0, H_HI-1) - (r0-1);
        cc[d] = iclamp(gx+d-1, 0, W_HI-1) - (c0-1);
      }
      for (int ic=0; ic<64; ic++){
        #pragma unroll
        for (int ky=0;ky<3;ky++){
          #pragma unroll
          for (int kx=0;kx<3;kx++){
            float v = s_h2[ic*196 + rr[ky]*14 + cc[kx]];
            int widx = ic*9 + ky*3 + kx;
            a0 += w3g[widx] * v;
            a1 += w3g[576 + widx] * v;
          }
        }
      }
      float alpha = fminf(fmaxf(a0, 0.0f), 1.0f);
      int pix = gy*W_HI + gx;
      const float* fp = FB + n*4*HW_HI + pix;
      const float* hp = hbase + pix;
      float* op = histOut + n*4*HW_HI + pix;
      float* rp = outp + n*3*HW_HI + pix;
      #pragma unroll
      for (int c=0;c<4;c++){
        float h = hp[c*HW_HI]*(1.0f-alpha) + fp[c*HW_HI]*alpha;
        if (c == 3) h += a1;
        h = fminf(fmaxf(h, 0.0f), 1.0f);
        op[c*HW_HI] = h;
        if (c < 3) rp[c*HW_HI] = h;
      }
    }
  }
}

extern "C" void kernel_launch(void* const* d_in, const int* in_sizes, int n_in,
                              void* d_out, int out_size, void* d_ws, size_t ws_size,
                              hipStream_t stream){
  const float* frames = (const float*)d_in[0];
  const float* depths = (const float*)d_in[1];
  const float* mvs    = (const float*)d_in[2];
  const float* jits   = (const float*)d_in[3];
  const float* w1 = (const float*)d_in[4];
  const float* b1 = (const float*)d_in[5];
  const float* w2 = (const float*)d_in[6];
  const float* b2 = (const float*)d_in[7];
  const float* w3 = (const float*)d_in[8];
  const float* b3 = (const float*)d_in[9];
  float* out = (float*)d_out;

  float* FBp = (float*)d_ws;                       // [N,4,720,1280]
  float* HA  = FBp + (size_t)NB*4*HW_HI;           // history ping
  float* HB  = HA  + (size_t)NB*4*HW_HI;           // history pong
  // total workspace use: 3 * 29,491,200 B = 88.5 MB

  dim3 bs(256);
  int npix = NB*HW_HI;
  dim3 gpix((npix + 255)/256);
  dim3 gfused((W_HI + TILE-1)/TILE, (H_HI + TILE-1)/TILE, NB);

  for (int t = T_STEPS-1; t >= 0; --t){
    const float* fr = frames + (size_t)t*NB*3*HW_LO;
    const float* dp = depths + (size_t)t*NB*HW_LO;
    const float* mv = mvs    + (size_t)t*NB*HW_LO*2;
    const float* jt = jits   + (size_t)t*NB*2;
    float* ot = out + (size_t)t*NB*3*HW_HI;

    k_prep<<<gpix, bs, 0, stream>>>(fr, dp, jt, FBp);
    const float* histIn;
    if (t == T_STEPS-1) {
      histIn = FBp;                 // history := frame_bicubic
    } else {
      k_warp<<<gpix, bs, 0, stream>>>(HA, mv, FBp, HB);
      histIn = HB;
    }
    k_fused<<<gfused, bs, 0, stream>>>(fr, dp, jt, histIn, FBp,
        w1, b1, w2, b2, w3, b3, HA, ot);
  }
}

// Round 2
// 3534.053 us; speedup vs baseline: 5.3666x; 5.3666x over previous
//
#include <hip/hip_runtime.h>

#define T_STEPS 3
#define NB 2
#define H_LO 360
#define W_LO 640
#define H_HI 720
#define W_HI 1280
#define HW_LO (H_LO*W_LO)
#define HW_HI (H_HI*W_HI)
#define TILE 12

typedef _Float16 f16;
typedef __attribute__((ext_vector_type(8))) _Float16 f16x8;
typedef __attribute__((ext_vector_type(4))) float f32x4;

// LDS byte offsets (total 135808 <= 160K)
#define OFF_W2  0            // 73728 B : w2 f16 [oc64][k576] swizzled
#define OFF_H1  73728        // 32768 B : h1 f16 [16][16][64] swizzled
#define OFF_H2  106496       // 25088 B : h2 f16 [14][14][64] swizzled (aliased below)
#define OFF_CNN OFF_H2       //  5184 B : cnn_in f16 [18][18][8]  (phase A/B only)
#define OFF_W1  (OFF_H2+5184)// 16384 B : w1 f16 [oc64][k128] swizzled (phase A/B only)
#define OFF_W3  131584       //  3072 B : w3 f16 [2][576] (+pad)
#define OFF_RES 134656       //  1152 B : conv3 result f32 [2][144]
#define LDS_BYTES 135808

__device__ __forceinline__ int imin(int a,int b){return a<b?a:b;}
__device__ __forceinline__ int imax(int a,int b){return a>b?a:b;}
__device__ __forceinline__ int iclamp(int v,int lo,int hi){return imin(imax(v,lo),hi);}

__device__ __forceinline__ float depth_tx(float d0){
  float d = 10.0f / (100.0f - d0*99.9f);
  return (d - 0.1f) / 99.9f;
}

__device__ __forceinline__ void cubw(float t, float* w){
  const float a = -0.75f;
  float t2 = t*t, t3 = t2*t;
  w[0] = a*(t3 - 2.0f*t2 + t);
  w[1] = (a+2.0f)*t3 - (a+3.0f)*t2 + 1.0f;
  float s = 1.0f - t;
  w[2] = (a+2.0f)*s*s*s - (a+3.0f)*s*s + 1.0f;
  float u = 2.0f - t;
  w[3] = a*u*u*u - 5.0f*a*u*u + 8.0f*a*u - 4.0f*a;
}

// ---------------- weight prep: f32 -> f16, relayout + XOR-swizzle, once per launch ----------------
// wbuf f16 layout: [0,8192) w1 [oc64][kk128]; [8192,45056) w2 [oc64][kk576]; [45056,46592) w3 [2][576]+pad
__global__ __launch_bounds__(256) void k_wprep(const float* __restrict__ w1g,
    const float* __restrict__ w2g, const float* __restrict__ w3g, f16* __restrict__ wbuf){
  int i = blockIdx.x*256 + threadIdx.x;
  if (i >= 46592) return;
  float val = 0.0f;
  if (i < 8192){
    int oc = i>>7, kk = i&127, k = kk ^ ((oc&7)<<3);      // k = tap*8+ic, pad [72,128)=0
    if (k < 72) val = w1g[(oc*8 + (k&7))*9 + (k>>3)];
  } else if (i < 45056){
    int j = i - 8192; int oc = j/576, kk = j - oc*576, k = kk ^ ((oc&7)<<3); // k = tap*64+ic
    val = w2g[(oc*64 + (k&63))*9 + (k>>6)];
  } else {
    int j = i - 45056;
    if (j < 1152){ int nn = j/576, k = j - nn*576;
      val = w3g[(nn*64 + (k&63))*9 + (k>>6)];
    }
  }
  wbuf[i] = (f16)val;
}

// ---------------- FB = bicubic jitter-aligned upsample of [frame, depth_tx] ----------------
__global__ __launch_bounds__(256) void k_prep(const float* __restrict__ frame,
    const float* __restrict__ depth, const float* __restrict__ jit,
    float* __restrict__ FB){
  int idx = blockIdx.x*256 + threadIdx.x;
  if (idx >= NB*HW_HI) return;
  int n = idx / HW_HI, p = idx - n*HW_HI;
  int y = p / W_HI, x = p - y*W_HI;
  float jx = jit[n*2], jy = jit[n*2+1];
  float gx = (2.0f*(float)x + 1.0f)/(float)W_HI - 1.0f + 2.0f*(0.5f - jx)/(float)W_LO;
  float gy = (2.0f*(float)y + 1.0f)/(float)H_HI - 1.0f + 2.0f*(0.5f - jy)/(float)H_LO;
  float ix = ((gx + 1.0f)*(float)W_LO - 1.0f)*0.5f;
  float iy = ((gy + 1.0f)*(float)H_LO - 1.0f)*0.5f;
  float xf = floorf(ix), yf = floorf(iy);
  float tx = ix - xf, ty = iy - yf;
  int xi = (int)xf, yi = (int)yf;
  float wx[4], wy[4]; cubw(tx, wx); cubw(ty, wy);
  int xs[4], ys[4];
  #pragma unroll
  for (int j=0;j<4;j++){ xs[j]=iclamp(xi-1+j,0,W_LO-1); ys[j]=iclamp(yi-1+j,0,H_LO-1); }
  const float* fb = frame + n*3*HW_LO;
  const float* db = depth + n*HW_LO;
  float a0=0.f,a1=0.f,a2=0.f,a3=0.f;
  #pragma unroll
  for (int i=0;i<4;i++){
    #pragma unroll
    for (int j=0;j<4;j++){
      float wgt = wy[i]*wx[j];
      int off = ys[i]*W_LO + xs[j];
      a0 += wgt*fb[off];
      a1 += wgt*fb[HW_LO+off];
      a2 += wgt*fb[2*HW_LO+off];
      a3 += wgt*depth_tx(db[off]);
    }
  }
  float* o = FB + n*4*HW_HI + p;
  o[0] = a0; o[HW_HI] = a1; o[2*HW_HI] = a2; o[3*HW_HI] = a3;
}

// ---------------- histB = bicubic warp of histA by bilinearly-upsampled mv; OOB -> FB ----------------
__global__ __launch_bounds__(256) void k_warp(const float* __restrict__ histA,
    const float* __restrict__ mv, const float* __restrict__ FB,
    float* __restrict__ histB){
  int idx = blockIdx.x*256 + threadIdx.x;
  if (idx >= NB*HW_HI) return;
  int n = idx / HW_HI, p = idx - n*HW_HI;
  int y = p / W_HI, x = p - y*W_HI;
  float cy = fmaxf(((float)y + 0.5f)/2.0f - 0.5f, 0.0f);
  float cx = fmaxf(((float)x + 0.5f)/2.0f - 0.5f, 0.0f);
  float y0f = floorf(cy), x0f = floorf(cx);
  float tyv = cy - y0f, txv = cx - x0f;
  int y0 = iclamp((int)y0f, 0, H_LO-1), y1 = iclamp((int)y0f+1, 0, H_LO-1);
  int x0 = iclamp((int)x0f, 0, W_LO-1), x1 = iclamp((int)x0f+1, 0, W_LO-1);
  const float* mb = mv + n*HW_LO*2;
  float gx, gy;
  {
    float v00 = mb[(y0*W_LO+x0)*2], v01 = mb[(y0*W_LO+x1)*2];
    float v10 = mb[(y1*W_LO+x0)*2], v11 = mb[(y1*W_LO+x1)*2];
    float r0 = v00*(1.0f-tyv) + v10*tyv;
    float r1 = v01*(1.0f-tyv) + v11*tyv;
    gx = r0*(1.0f-txv) + r1*txv;
  }
  {
    float v00 = mb[(y0*W_LO+x0)*2+1], v01 = mb[(y0*W_LO+x1)*2+1];
    float v10 = mb[(y1*W_LO+x0)*2+1], v11 = mb[(y1*W_LO+x1)*2+1];
    float r0 = v00*(1.0f-tyv) + v10*tyv;
    float r1 = v01*(1.0f-tyv) + v11*tyv;
    gy = r0*(1.0f-txv) + r1*txv;
  }
  bool oob = (gx > 1.0f) || (gx < -1.0f) || (gy > 1.0f) || (gy < -1.0f);
  const float* hb = histA + n*4*HW_HI;
  float* ob = histB + n*4*HW_HI + p;
  if (oob) {
    const float* f = FB + n*4*HW_HI + p;
    #pragma unroll
    for (int c=0;c<4;c++) ob[c*HW_HI] = f[c*HW_HI];
  } else {
    float ix = ((gx + 1.0f)*(float)W_HI - 1.0f)*0.5f;
    float iy = ((gy + 1.0f)*(float)H_HI - 1.0f)*0.5f;
    float xf = floorf(ix), yf = floorf(iy);
    float tx = ix - xf, ty = iy - yf;
    int xi = (int)xf, yi = (int)yf;
    float wx[4], wy[4]; cubw(tx, wx); cubw(ty, wy);
    int xs[4], ys[4];
    #pragma unroll
    for (int j=0;j<4;j++){ xs[j]=iclamp(xi-1+j,0,W_HI-1); ys[j]=iclamp(yi-1+j,0,H_HI-1); }
    float a0=0.f,a1=0.f,a2=0.f,a3=0.f;
    #pragma unroll
    for (int i=0;i<4;i++){
      #pragma unroll
      for (int j=0;j<4;j++){
        float wgt = wy[i]*wx[j];
        int off = ys[i]*W_HI + xs[j];
        a0 += wgt*hb[off];
        a1 += wgt*hb[HW_HI+off];
        a2 += wgt*hb[2*HW_HI+off];
        a3 += wgt*hb[3*HW_HI+off];
      }
    }
    ob[0] = a0; ob[HW_HI] = a1; ob[2*HW_HI] = a2; ob[3*HW_HI] = a3;
  }
}

// ---------------- fused conv1+conv2+conv3 (MFMA f16) + blend, one 12x12 output tile per block ----------------
__global__ __launch_bounds__(256,1) void k_fused(
    const float* __restrict__ frame, const float* __restrict__ depth,
    const float* __restrict__ jit, const float* __restrict__ histIn,
    const float* __restrict__ FB, const f16* __restrict__ wbuf,
    const float* __restrict__ b1g, const float* __restrict__ b2g, const float* __restrict__ b3g,
    float* __restrict__ histOut, float* __restrict__ outp)
{
  __shared__ __attribute__((aligned(16))) char smem[LDS_BYTES];
  const int tid = threadIdx.x;
  const int wv = tid>>6, ln = tid&63, lr = ln&15, lq = ln>>4;
  const int n  = blockIdx.z;
  const int r0 = blockIdx.y * TILE;
  const int c0 = blockIdx.x * TILE;
  const float jx = jit[n*2], jy = jit[n*2+1];
  const int jix = (int)floorf(jx*2.0f), jiy = (int)floorf(jy*2.0f);
  const float* fbase = frame + n*3*HW_LO;
  const float* dbase = depth + n*HW_LO;
  const float* hbase = histIn + (size_t)n*4*HW_HI;

  // ---- Stage: weights (pre-swizzled f16 in global) + cnn_in tile ----
  for (int i=tid; i<1024; i+=256) *(float4*)(smem+OFF_W1+i*16) = *(const float4*)((const char*)wbuf + i*16);
  for (int i=tid; i<4608; i+=256) *(float4*)(smem+OFF_W2+i*16) = *(const float4*)((const char*)wbuf + 16384 + i*16);
  for (int i=tid; i<192;  i+=256) *(float4*)(smem+OFF_W3+i*16) = *(const float4*)((const char*)wbuf + 90112 + i*16);

  for (int e=tid; e<324; e+=256){
    int u = e/18, v = e - u*18;
    int cgy = iclamp(r0-3+u, 0, H_HI-1);
    int cgx = iclamp(c0-3+v, 0, W_HI-1);
    float v0=0.f, v1=0.f, v2=0.f, v3=0.f;
    int yy = cgy - jiy, xx = cgx - jix;
    if (yy>=0 && xx>=0 && !(yy&1) && !(xx&1)){
      int ys = yy>>1, xs = xx>>1;
      int off = ys*W_LO + xs;
      v0 = fbase[off]; v1 = fbase[HW_LO+off]; v2 = fbase[2*HW_LO+off];
      v3 = depth_tx(dbase[off]);
    }
    int pix = cgy*W_HI + cgx;
    f16x8 pk;
    pk[0]=(f16)v0; pk[1]=(f16)v1; pk[2]=(f16)v2; pk[3]=(f16)v3;
    pk[4]=(f16)hbase[pix];        pk[5]=(f16)hbase[HW_HI+pix];
    pk[6]=(f16)hbase[2*HW_HI+pix];pk[7]=(f16)hbase[3*HW_HI+pix];
    *(f16x8*)(smem + OFF_CNN + e*16) = pk;
  }
  __syncthreads();

  // ---- conv1: M=256(16x16 halo grid), N=64, K=72(pad 96), k = tap*8+ic ----
  {
    f16x8 B1[3][4];
    #pragma unroll
    for (int kc=0;kc<3;kc++)
      #pragma unroll
      for (int oct=0;oct<4;oct++){
        int oc = oct*16 + lr;
        int k0 = kc*32 + lq*8;
        B1[kc][oct] = *(const f16x8*)(smem + OFF_W1 + ((oc*128 + (k0 ^ ((oc&7)<<3)))<<1));
      }
    float b1v[4];
    #pragma unroll
    for (int oct=0;oct<4;oct++) b1v[oct] = b1g[oct*16+lr];
    #pragma unroll
    for (int ty4=0;ty4<4;ty4++){
      int ty = wv*4 + ty4;
      int g1y = iclamp(r0-2+ty, 0, H_HI-1);
      int g1x = iclamp(c0-2+lr, 0, W_HI-1);
      f32x4 acc[4];
      #pragma unroll
      for (int oct=0;oct<4;oct++) acc[oct] = (f32x4){b1v[oct],b1v[oct],b1v[oct],b1v[oct]};
      #pragma unroll
      for (int kc=0;kc<3;kc++){
        int k0 = kc*32 + lq*8;
        int t = imin(k0>>3, 8);
        int dy = (t*11)>>5; int dx = t - dy*3;
        int uu = iclamp(g1y+dy-1, 0, H_HI-1) - (r0-3);
        int vv = iclamp(g1x+dx-1, 0, W_HI-1) - (c0-3);
        f16x8 a = *(const f16x8*)(smem + OFF_CNN + (uu*18+vv)*16);
        #pragma unroll
        for (int oct=0;oct<4;oct++)
          acc[oct] = __builtin_amdgcn_mfma_f32_16x16x32_f16(a, B1[kc][oct], acc[oct], 0,0,0);
      }
      #pragma unroll
      for (int oct=0;oct<4;oct++){
        int oc = oct*16 + lr;
        #pragma unroll
        for (int reg=0;reg<4;reg++){
          int tx = lq*4 + reg;
          *(f16*)(smem + OFF_H1 + (((ty*16+tx)*64 + (oc ^ ((tx&7)<<3)))<<1)) = (f16)fmaxf(acc[oct][reg], 0.f);
        }
      }
    }
  }
  __syncthreads();

  // ---- conv2: M=196(14x14, 13 tiles), N=64, K=576, k = tap*64+ic ----
  {
    const int nmt = (wv==0) ? 4 : 3;
    const int mtid[4] = {wv, 4+wv, 8+wv, 12};
    int rowOf[4][3], colc[4][3][2];
    #pragma unroll
    for (int mti=0;mti<4;mti++){
      int m = imin(mtid[mti]*16 + lr, 195);
      int py = m/14, px = m - py*14;
      int Ay = iclamp(r0-1+py, 0, H_HI-1);
      int Ax = iclamp(c0-1+px, 0, W_HI-1);
      #pragma unroll
      for (int d=0;d<3;d++){
        rowOf[mti][d] = (iclamp(Ay+d-1, 0, H_HI-1) - (r0-2))*1024;  // *16*64 (f16 elems)
        int vv = iclamp(Ax+d-1, 0, W_HI-1) - (c0-2);
        int key = (vv&7)<<3;
        colc[mti][d][0] = vv*64 + ((lq*8) ^ key);
        colc[mti][d][1] = vv*64 + ((32+lq*8) ^ key);
      }
    }
    float b2v[4];
    #pragma unroll
    for (int oct=0;oct<4;oct++) b2v[oct] = b2g[oct*16+lr];
    f32x4 acc2[4][4];
    #pragma unroll
    for (int mti=0;mti<4;mti++)
      #pragma unroll
      for (int oct=0;oct<4;oct++) acc2[mti][oct] = (f32x4){b2v[oct],b2v[oct],b2v[oct],b2v[oct]};
    int wb[4], wk[4];
    #pragma unroll
    for (int oct=0;oct<4;oct++){ int oc = oct*16+lr; wb[oct] = oc*1152; wk[oct] = (oc&7)<<3; }
    #pragma unroll
    for (int kc=0;kc<18;kc++){
      const int tap = kc>>1, half = kc&1;
      const int dy = tap/3, dx = tap - dy*3;
      int k0 = kc*32 + lq*8;
      f16x8 bf[4];
      #pragma unroll
      for (int oct=0;oct<4;oct++)
        bf[oct] = *(const f16x8*)(smem + OFF_W2 + wb[oct] + ((k0 ^ wk[oct])<<1));
      #pragma unroll
      for (int mti=0;mti<4;mti++) if (mti < nmt){
        f16x8 a = *(const f16x8*)(smem + OFF_H1 + ((rowOf[mti][dy] + colc[mti][dx][half])<<1));
        #pragma unroll
        for (int oct=0;oct<4;oct++)
          acc2[mti][oct] = __builtin_amdgcn_mfma_f32_16x16x32_f16(a, bf[oct], acc2[mti][oct], 0,0,0);
      }
    }
    // write h2 (relu, swizzled)
    #pragma unroll
    for (int mti=0;mti<4;mti++) if (mti < nmt){
      #pragma unroll
      for (int reg=0;reg<4;reg++){
        int m = mtid[mti]*16 + lq*4 + reg;
        if (m < 196){
          int py = m/14, px = m - py*14;
          int base = (py*14+px)*64; int key = (px&7)<<3;
          #pragma unroll
          for (int oct=0;oct<4;oct++){
            int oc = oct*16 + lr;
            *(f16*)(smem + OFF_H2 + ((base + (oc ^ key))<<1)) = (f16)fmaxf(acc2[mti][oct][reg], 0.f);
          }
        }
      }
    }
  }
  __syncthreads();

  // ---- conv3: M=144(12x12, 9 tiles), N=2(pad 16), K=576 ----
  {
    const int nm3 = (wv==0) ? 3 : 2;
    const int m3t[3] = {wv, 4+wv, 8};
    int rowOf[3][3], colc[3][3][2];
    #pragma unroll
    for (int i=0;i<3;i++){
      int m = m3t[i]*16 + lr;           // < 144
      int py = m/12, px = m - py*12;
      int Cy = r0 + py;                 // always < H_HI
      int Cx = iclamp(c0+px, 0, W_HI-1);
      #pragma unroll
      for (int d=0;d<3;d++){
        rowOf[i][d] = (iclamp(Cy+d-1, 0, H_HI-1) - (r0-1))*896;  // *14*64
        int vv = iclamp(Cx+d-1, 0, W_HI-1) - (c0-1);
        int key = (vv&7)<<3;
        colc[i][d][0] = vv*64 + ((lq*8) ^ key);
        colc[i][d][1] = vv*64 + ((32+lq*8) ^ key);
      }
    }
    f32x4 acc3[3] = {{0,0,0,0},{0,0,0,0},{0,0,0,0}};
    const int cidx = ln&1;
    #pragma unroll
    for (int kc=0;kc<18;kc++){
      const int tap = kc>>1, half = kc&1;
      const int dy = tap/3, dx = tap - dy*3;
      int k0 = kc*32 + lq*8;
      f16x8 b = *(const f16x8*)(smem + OFF_W3 + ((cidx*576 + k0)<<1));
      #pragma unroll
      for (int i=0;i<3;i++) if (i < nm3){
        f16x8 a = *(const f16x8*)(smem + OFF_H2 + ((rowOf[i][dy] + colc[i][dx][half])<<1));
        acc3[i] = __builtin_amdgcn_mfma_f32_16x16x32_f16(a, b, acc3[i], 0,0,0);
      }
    }
    float* sres = (float*)(smem + OFF_RES);
    if (lr < 2){
      float bv = b3g[lr];
      #pragma unroll
      for (int i=0;i<3;i++) if (i < nm3){
        #pragma unroll
        for (int reg=0;reg<4;reg++){
          int m = m3t[i]*16 + lq*4 + reg;
          sres[lr*144 + m] = acc3[i][reg] + bv;
        }
      }
    }
  }
  __syncthreads();

  // ---- blend + outputs over 12x12 ----
  if (tid < 144){
    int ty = tid/12, tx = tid - ty*12;
    int gy = r0 + ty, gx = c0 + tx;
    if (gx < W_HI){
      const float* sres = (const float*)(smem + OFF_RES);
      float a0 = sres[tid], a1 = sres[144+tid];
      float alpha = fminf(fmaxf(a0, 0.0f), 1.0f);
      int pix = gy*W_HI + gx;
      const float* fp = FB + (size_t)n*4*HW_HI + pix;
      const float* hp = hbase + pix;
      float* op = histOut + (size_t)n*4*HW_HI + pix;
      float* rp = outp + (size_t)n*3*HW_HI + pix;
      #pragma unroll
      for (int c=0;c<4;c++){
        float h = hp[c*HW_HI]*(1.0f-alpha) + fp[c*HW_HI]*alpha;
        if (c == 3) h += a1;
        h = fminf(fmaxf(h, 0.0f), 1.0f);
        op[c*HW_HI] = h;
        if (c < 3) rp[c*HW_HI] = h;
      }
    }
  }
}

extern "C" void kernel_launch(void* const* d_in, const int* in_sizes, int n_in,
                              void* d_out, int out_size, void* d_ws, size_t ws_size,
                              hipStream_t stream){
  const float* frames = (const float*)d_in[0];
  const float* depths = (const float*)d_in[1];
  const float* mvs    = (const float*)d_in[2];
  const float* jits   = (const float*)d_in[3];
  const float* w1 = (const float*)d_in[4];
  const float* b1 = (const float*)d_in[5];
  const float* w2 = (const float*)d_in[6];
  const float* b2 = (const float*)d_in[7];
  const float* w3 = (const float*)d_in[8];
  const float* b3 = (const float*)d_in[9];
  float* out = (float*)d_out;

  float* FBp = (float*)d_ws;                       // [N,4,720,1280] f32
  float* HA  = FBp + (size_t)NB*4*HW_HI;           // history ping
  float* HB  = HA  + (size_t)NB*4*HW_HI;           // history pong
  f16*  wbuf = (f16*)(HB + (size_t)NB*4*HW_HI);    // 46592 f16 = 93184 B
  // total workspace: 88,473,600 + 93,184 B

  dim3 bs(256);
  int npix = NB*HW_HI;
  dim3 gpix((npix + 255)/256);
  dim3 gfused((W_HI + TILE-1)/TILE, (H_HI + TILE-1)/TILE, NB);

  k_wprep<<<dim3((46592+255)/256), bs, 0, stream>>>(w1, w2, w3, wbuf);

  for (int t = T_STEPS-1; t >= 0; --t){
    const float* fr = frames + (size_t)t*NB*3*HW_LO;
    const float* dp = depths + (size_t)t*NB*HW_LO;
    const float* mv = mvs    + (size_t)t*NB*HW_LO*2;
    const float* jt = jits   + (size_t)t*NB*2;
    float* ot = out + (size_t)t*NB*3*HW_HI;

    k_prep<<<gpix, bs, 0, stream>>>(fr, dp, jt, FBp);
    const float* histIn;
    if (t == T_STEPS-1) {
      histIn = FBp;
    } else {
      k_warp<<<gpix, bs, 0, stream>>>(HA, mv, FBp, HB);
      histIn = HB;
    }
    k_fused<<<gfused, bs, 0, stream>>>(fr, dp, jt, histIn, FBp, wbuf,
        b1, b2, b3, HA, ot);
  }
}

// Round 5
// 2550.886 us; speedup vs baseline: 7.4350x; 1.3854x over previous
//
#include <hip/hip_runtime.h>

#define T_STEPS 3
#define NB 2
#define H_LO 360
#define W_LO 640
#define H_HI 720
#define W_HI 1280
#define HW_LO (H_LO*W_LO)
#define HW_HI (H_HI*W_HI)
#define TILE 12

typedef _Float16 f16;
typedef __attribute__((ext_vector_type(8))) _Float16 f16x8;
typedef __attribute__((ext_vector_type(4))) float f32x4;

// LDS byte offsets (total 69504 <= 81920 for 2 blocks/CU)
#define OFF_W2  0              //  8192 B : w2 single buffer, one tap [64oc][64ic swz] f16
#define OFF_H1  8192           // 32768 B : h1 f16 [16][16][64 swz]
#define OFF_H2  40960          // 25088 B : h2 f16 [14][14][64 swz]
#define OFF_CNN OFF_H2         //  5184 B : cnn_in f16 [18][18][8] (alias, dead before h2 written)
#define OFF_W1  (OFF_H2+5184)  // 16384 B : w1 f16 [oc64][kk128 swz] (alias, dead before h2 written)
#define OFF_W3  66048          //  2304 B : w3 f16 [2][576]
#define OFF_RES 68352          //  1152 B : conv3 result f32 [2][144]
#define LDS_BYTES 69504

__device__ __forceinline__ int imin(int a,int b){return a<b?a:b;}
__device__ __forceinline__ int imax(int a,int b){return a>b?a:b;}
__device__ __forceinline__ int iclamp(int v,int lo,int hi){return imin(imax(v,lo),hi);}

__device__ __forceinline__ float depth_tx(float d0){
  float d = 10.0f / (100.0f - d0*99.9f);
  return (d - 0.1f) / 99.9f;
}

__device__ __forceinline__ void cubw(float t, float* w){
  const float a = -0.75f;
  float t2 = t*t, t3 = t2*t;
  w[0] = a*(t3 - 2.0f*t2 + t);
  w[1] = (a+2.0f)*t3 - (a+3.0f)*t2 + 1.0f;
  float s = 1.0f - t;
  w[2] = (a+2.0f)*s*s*s - (a+3.0f)*s*s + 1.0f;
  float u = 2.0f - t;
  w[3] = a*u*u*u - 5.0f*a*u*u + 8.0f*a*u - 4.0f*a;
}

// ---------------- FB = bicubic jitter-aligned upsample of [frame, depth_tx] ----------------
__global__ __launch_bounds__(256) void k_prep(const float* __restrict__ frame,
    const float* __restrict__ depth, const float* __restrict__ jit,
    float* __restrict__ FB){
  int idx = blockIdx.x*256 + threadIdx.x;
  if (idx >= NB*HW_HI) return;
  int n = idx / HW_HI, p = idx - n*HW_HI;
  int y = p / W_HI, x = p - y*W_HI;
  float jx = jit[n*2], jy = jit[n*2+1];
  float gx = (2.0f*(float)x + 1.0f)/(float)W_HI - 1.0f + 2.0f*(0.5f - jx)/(float)W_LO;
  float gy = (2.0f*(float)y + 1.0f)/(float)H_HI - 1.0f + 2.0f*(0.5f - jy)/(float)H_LO;
  float ix = ((gx + 1.0f)*(float)W_LO - 1.0f)*0.5f;
  float iy = ((gy + 1.0f)*(float)H_LO - 1.0f)*0.5f;
  float xf = floorf(ix), yf = floorf(iy);
  float tx = ix - xf, ty = iy - yf;
  int xi = (int)xf, yi = (int)yf;
  float wx[4], wy[4]; cubw(tx, wx); cubw(ty, wy);
  int xs[4], ys[4];
  #pragma unroll
  for (int j=0;j<4;j++){ xs[j]=iclamp(xi-1+j,0,W_LO-1); ys[j]=iclamp(yi-1+j,0,H_LO-1); }
  const float* fb = frame + n*3*HW_LO;
  const float* db = depth + n*HW_LO;
  float a0=0.f,a1=0.f,a2=0.f,a3=0.f;
  #pragma unroll
  for (int i=0;i<4;i++){
    #pragma unroll
    for (int j=0;j<4;j++){
      float wgt = wy[i]*wx[j];
      int off = ys[i]*W_LO + xs[j];
      a0 += wgt*fb[off];
      a1 += wgt*fb[HW_LO+off];
      a2 += wgt*fb[2*HW_LO+off];
      a3 += wgt*depth_tx(db[off]);
    }
  }
  float* o = FB + n*4*HW_HI + p;
  o[0] = a0; o[HW_HI] = a1; o[2*HW_HI] = a2; o[3*HW_HI] = a3;
}

// ---------------- weight prep (EXACT R2 layout): f32 -> f16, relayout + XOR-swizzle ----------------
// wbuf f16: [0,8192) w1 [oc64][kk128]; [8192,45056) w2 [oc64][kk576]; [45056,46208) w3 [2][576]; pad to 46592
__global__ __launch_bounds__(256) void k_wprep(const float* __restrict__ w1g,
    const float* __restrict__ w2g, const float* __restrict__ w3g, f16* __restrict__ wbuf){
  int i = blockIdx.x*256 + threadIdx.x;
  if (i >= 46592) return;
  float val = 0.0f;
  if (i < 8192){
    int oc = i>>7, kk = i&127, k = kk ^ ((oc&7)<<3);      // k = tap*8+ic, pad [72,128)=0
    if (k < 72) val = w1g[(oc*8 + (k&7))*9 + (k>>3)];
  } else if (i < 45056){
    int j = i - 8192; int oc = j/576, kk = j - oc*576, k = kk ^ ((oc&7)<<3); // k = tap*64+ic
    val = w2g[(oc*64 + (k&63))*9 + (k>>6)];
  } else {
    int j = i - 45056;
    if (j < 1152){ int nn = j/576, k = j - nn*576;
      val = w3g[(nn*64 + (k&63))*9 + (k>>6)];
    }
  }
  wbuf[i] = (f16)val;
}

// ---------------- histB = bicubic warp of histA (planar) by bilinear mv; OOB -> FB ----------------
__global__ __launch_bounds__(256) void k_warp(const float* __restrict__ histA,
    const float* __restrict__ mv, const float* __restrict__ FB,
    float* __restrict__ histB){
  int idx = blockIdx.x*256 + threadIdx.x;
  if (idx >= NB*HW_HI) return;
  int n = idx / HW_HI, p = idx - n*HW_HI;
  int y = p / W_HI, x = p - y*W_HI;
  float cy = fmaxf(((float)y + 0.5f)/2.0f - 0.5f, 0.0f);
  float cx = fmaxf(((float)x + 0.5f)/2.0f - 0.5f, 0.0f);
  float y0f = floorf(cy), x0f = floorf(cx);
  float tyv = cy - y0f, txv = cx - x0f;
  int y0 = iclamp((int)y0f, 0, H_LO-1), y1 = iclamp((int)y0f+1, 0, H_LO-1);
  int x0 = iclamp((int)x0f, 0, W_LO-1), x1 = iclamp((int)x0f+1, 0, W_LO-1);
  const float* mb = mv + (size_t)n*HW_LO*2;
  float gx, gy;
  {
    float v00 = mb[(y0*W_LO+x0)*2], v01 = mb[(y0*W_LO+x1)*2];
    float v10 = mb[(y1*W_LO+x0)*2], v11 = mb[(y1*W_LO+x1)*2];
    float r0 = v00*(1.0f-tyv) + v10*tyv;
    float r1 = v01*(1.0f-tyv) + v11*tyv;
    gx = r0*(1.0f-txv) + r1*txv;
  }
  {
    float v00 = mb[(y0*W_LO+x0)*2+1], v01 = mb[(y0*W_LO+x1)*2+1];
    float v10 = mb[(y1*W_LO+x0)*2+1], v11 = mb[(y1*W_LO+x1)*2+1];
    float r0 = v00*(1.0f-tyv) + v10*tyv;
    float r1 = v01*(1.0f-tyv) + v11*tyv;
    gy = r0*(1.0f-txv) + r1*txv;
  }
  bool oob = (gx > 1.0f) || (gx < -1.0f) || (gy > 1.0f) || (gy < -1.0f);
  const float* hb = histA + (size_t)n*4*HW_HI;
  float* ob = histB + (size_t)n*4*HW_HI + p;
  if (oob) {
    const float* f = FB + (size_t)n*4*HW_HI + p;
    #pragma unroll
    for (int c=0;c<4;c++) ob[c*HW_HI] = f[c*HW_HI];
  } else {
    float ix = ((gx + 1.0f)*(float)W_HI - 1.0f)*0.5f;
    float iy = ((gy + 1.0f)*(float)H_HI - 1.0f)*0.5f;
    float xf = floorf(ix), yf = floorf(iy);
    float tx = ix - xf, ty = iy - yf;
    int xi = (int)xf, yi = (int)yf;
    float wx[4], wy[4]; cubw(tx, wx); cubw(ty, wy);
    int xs[4], ys[4];
    #pragma unroll
    for (int j=0;j<4;j++){ xs[j]=iclamp(xi-1+j,0,W_HI-1); ys[j]=iclamp(yi-1+j,0,H_HI-1); }
    float a0=0.f,a1=0.f,a2=0.f,a3=0.f;
    #pragma unroll
    for (int i=0;i<4;i++){
      #pragma unroll
      for (int j=0;j<4;j++){
        float wgt = wy[i]*wx[j];
        int off = ys[i]*W_HI + xs[j];
        a0 += wgt*hb[off];
        a1 += wgt*hb[HW_HI+off];
        a2 += wgt*hb[2*HW_HI+off];
        a3 += wgt*hb[3*HW_HI+off];
      }
    }
    ob[0] = a0; ob[HW_HI] = a1; ob[2*HW_HI] = a2; ob[3*HW_HI] = a3;
  }
}

// ---------------- fused conv1+conv2+conv3 (MFMA f16) + blend, 12x12 tile/block ----------------
__global__ __launch_bounds__(256,2) void k_fused(
    const float* __restrict__ frame, const float* __restrict__ depth,
    const float* __restrict__ jit, const float* __restrict__ histIn,
    const float* __restrict__ FB, const f16* __restrict__ wbuf,
    const float* __restrict__ b1g, const float* __restrict__ b2g, const float* __restrict__ b3g,
    float* __restrict__ histOut, float* __restrict__ outp)
{
  __shared__ __attribute__((aligned(16))) char smem[LDS_BYTES];
  const int tid = threadIdx.x;
  const int wv = tid>>6, ln = tid&63, lr = ln&15, lq = ln>>4;
  const int n  = blockIdx.z;
  const int r0 = blockIdx.y * TILE;
  const int c0 = blockIdx.x * TILE;
  const float jx = jit[n*2], jy = jit[n*2+1];
  const int jix = (int)floorf(jx*2.0f), jiy = (int)floorf(jy*2.0f);
  const float* fbase = frame + (size_t)n*3*HW_LO;
  const float* dbase = depth + (size_t)n*HW_LO;
  const float* hbase = histIn + (size_t)n*4*HW_HI;

  // ---- Stage A: w1 + w3 staging, cnn_in tile (18x18x8) ----
  for (int i=tid; i<1024; i+=256) *(float4*)(smem+OFF_W1+i*16) = *(const float4*)((const char*)wbuf + i*16);
  const float4* w3src = (const float4*)(wbuf + 45056);
  for (int i=tid; i<144; i+=256) ((float4*)(smem + OFF_W3))[i] = w3src[i];

  for (int e=tid; e<324; e+=256){
    int u = e/18, v = e - u*18;
    int cgy = iclamp(r0-3+u, 0, H_HI-1);
    int cgx = iclamp(c0-3+v, 0, W_HI-1);
    float v0=0.f, v1=0.f, v2=0.f, v3=0.f;
    int yy = cgy - jiy, xx = cgx - jix;
    if (yy>=0 && xx>=0 && !(yy&1) && !(xx&1)){
      int off = (yy>>1)*W_LO + (xx>>1);
      v0 = fbase[off]; v1 = fbase[HW_LO+off]; v2 = fbase[2*HW_LO+off];
      v3 = depth_tx(dbase[off]);
    }
    int pix = cgy*W_HI + cgx;
    f16x8 pk;
    pk[0]=(f16)v0; pk[1]=(f16)v1; pk[2]=(f16)v2; pk[3]=(f16)v3;
    pk[4]=(f16)hbase[pix];        pk[5]=(f16)hbase[HW_HI+pix];
    pk[6]=(f16)hbase[2*HW_HI+pix];pk[7]=(f16)hbase[3*HW_HI+pix];
    *(f16x8*)(smem + OFF_CNN + e*16) = pk;
  }
  __syncthreads();

  // ---- conv1: M=256(16x16 halo grid), N=64, K=72(pad 96), k = tap*8+ic ----
  {
    f16x8 B1[3][4];
    #pragma unroll
    for (int kc=0;kc<3;kc++)
      #pragma unroll
      for (int oct=0;oct<4;oct++){
        int oc = oct*16 + lr;
        int k0 = kc*32 + lq*8;
        B1[kc][oct] = *(const f16x8*)(smem + OFF_W1 + ((oc*128 + (k0 ^ ((oc&7)<<3)))<<1));
      }
    float b1v[4];
    #pragma unroll
    for (int oct=0;oct<4;oct++) b1v[oct] = b1g[oct*16+lr];
    #pragma unroll
    for (int ty4=0;ty4<4;ty4++){
      int ty = wv*4 + ty4;
      int g1y = iclamp(r0-2+ty, 0, H_HI-1);
      int g1x = iclamp(c0-2+lr, 0, W_HI-1);
      f32x4 acc[4];
      #pragma unroll
      for (int oct=0;oct<4;oct++) acc[oct] = (f32x4){b1v[oct],b1v[oct],b1v[oct],b1v[oct]};
      #pragma unroll
      for (int kc=0;kc<3;kc++){
        int k0 = kc*32 + lq*8;
        int t = imin(k0>>3, 8);
        int dy = (t*11)>>5; int dx = t - dy*3;
        int uu = iclamp(g1y+dy-1, 0, H_HI-1) - (r0-3);
        int vv = iclamp(g1x+dx-1, 0, W_HI-1) - (c0-3);
        f16x8 a = *(const f16x8*)(smem + OFF_CNN + (uu*18+vv)*16);
        #pragma unroll
        for (int oct=0;oct<4;oct++)
          acc[oct] = __builtin_amdgcn_mfma_f32_16x16x32_f16(a, B1[kc][oct], acc[oct], 0,0,0);
      }
      #pragma unroll
      for (int oct=0;oct<4;oct++){
        int oc = oct*16 + lr;
        #pragma unroll
        for (int reg=0;reg<4;reg++){
          int tx = lq*4 + reg;
          *(f16*)(smem + OFF_H1 + (((ty*16+tx)*64 + (oc ^ ((tx&7)<<3)))<<1)) = (f16)fmaxf(acc[oct][reg], 0.f);
        }
      }
    }
  }
  __syncthreads();

  // ---- conv2: M=196(14x14, 13 tiles), N=64, K=576; w2 staged per tap, single buffer ----
  {
    const int nmt = (wv==0) ? 4 : 3;
    const int mtid[4] = {wv, 4+wv, 8+wv, 12};
    int rowOf[4][3], colc[4][3][2];
    #pragma unroll
    for (int mti=0;mti<4;mti++){
      int m = imin(mtid[mti]*16 + lr, 195);
      int py = m/14, px = m - py*14;
      int Ay = iclamp(r0-1+py, 0, H_HI-1);
      int Ax = iclamp(c0-1+px, 0, W_HI-1);
      #pragma unroll
      for (int d=0;d<3;d++){
        rowOf[mti][d] = (iclamp(Ay+d-1, 0, H_HI-1) - (r0-2))*1024;  // *16*64
        int vv = iclamp(Ax+d-1, 0, W_HI-1) - (c0-2);
        int key = (vv&7)<<3;
        colc[mti][d][0] = vv*64 + ((lq*8) ^ key);
        colc[mti][d][1] = vv*64 + ((32+lq*8) ^ key);
      }
    }
    float b2v[4];
    #pragma unroll
    for (int oct=0;oct<4;oct++) b2v[oct] = b2g[oct*16+lr];
    f32x4 acc2[4][4];
    #pragma unroll
    for (int mti=0;mti<4;mti++)
      #pragma unroll
      for (int oct=0;oct<4;oct++) acc2[mti][oct] = (f32x4){b2v[oct],b2v[oct],b2v[oct],b2v[oct]};
    int wb[4], wk[4];
    #pragma unroll
    for (int oct=0;oct<4;oct++){ int oc = oct*16+lr; wb[oct] = oc*64; wk[oct] = (oc&7)<<3; }
    const float4* w2src = (const float4*)(wbuf + 8192);   // [oc64][72 float4]
    for (int tap=0;tap<9;tap++){
      __syncthreads();   // prior tap's readers done before overwrite
      for (int i=tid;i<512;i+=256){
        int oc = i>>3, q = i&7;
        ((float4*)(smem + OFF_W2))[i] = w2src[oc*72 + tap*8 + q];
      }
      __syncthreads();   // staging visible
      const int dy = tap/3, dx = tap - dy*3;
      #pragma unroll
      for (int half=0; half<2; half++){
        int k0l = half*32 + lq*8;
        f16x8 bf[4];
        #pragma unroll
        for (int oct=0;oct<4;oct++)
          bf[oct] = *(const f16x8*)(smem + OFF_W2 + ((wb[oct] + (k0l ^ wk[oct]))<<1));
        #pragma unroll
        for (int mti=0;mti<4;mti++) if (mti < nmt){
          f16x8 a = *(const f16x8*)(smem + OFF_H1 + ((rowOf[mti][dy] + colc[mti][dx][half])<<1));
          #pragma unroll
          for (int oct=0;oct<4;oct++)
            acc2[mti][oct] = __builtin_amdgcn_mfma_f32_16x16x32_f16(a, bf[oct], acc2[mti][oct], 0,0,0);
        }
      }
    }
    __syncthreads();
    // write h2 (relu, swizzled)
    #pragma unroll
    for (int mti=0;mti<4;mti++) if (mti < nmt){
      #pragma unroll
      for (int reg=0;reg<4;reg++){
        int m = mtid[mti]*16 + lq*4 + reg;
        if (m < 196){
          int py = m/14, px = m - py*14;
          int base = (py*14+px)*64; int key = (px&7)<<3;
          #pragma unroll
          for (int oct=0;oct<4;oct++){
            int oc = oct*16 + lr;
            *(f16*)(smem + OFF_H2 + ((base + (oc ^ key))<<1)) = (f16)fmaxf(acc2[mti][oct][reg], 0.f);
          }
        }
      }
    }
  }
  __syncthreads();

  // ---- conv3: M=144(12x12, 9 tiles), N=2(pad 16), K=576 ----
  {
    const int nm3 = (wv==0) ? 3 : 2;
    const int m3t[3] = {wv, 4+wv, 8};
    int rowOf[3][3], colc[3][3][2];
    #pragma unroll
    for (int i=0;i<3;i++){
      int m = m3t[i]*16 + lr;           // < 144
      int py = m/12, px = m - py*12;
      int Cy = r0 + py;
      int Cx = iclamp(c0+px, 0, W_HI-1);
      #pragma unroll
      for (int d=0;d<3;d++){
        rowOf[i][d] = (iclamp(Cy+d-1, 0, H_HI-1) - (r0-1))*896;  // *14*64
        int vv = iclamp(Cx+d-1, 0, W_HI-1) - (c0-1);
        int key = (vv&7)<<3;
        colc[i][d][0] = vv*64 + ((lq*8) ^ key);
        colc[i][d][1] = vv*64 + ((32+lq*8) ^ key);
      }
    }
    f32x4 acc3[3] = {{0,0,0,0},{0,0,0,0},{0,0,0,0}};
    const int cidx = ln&1;
    #pragma unroll
    for (int kc=0;kc<18;kc++){
      const int tap = kc>>1, half = kc&1;
      const int dy = tap/3, dx = tap - dy*3;
      int k0 = kc*32 + lq*8;
      f16x8 b = *(const f16x8*)(smem + OFF_W3 + ((cidx*576 + k0)<<1));
      #pragma unroll
      for (int i=0;i<3;i++) if (i < nm3){
        f16x8 a = *(const f16x8*)(smem + OFF_H2 + ((rowOf[i][dy] + colc[i][dx][half])<<1));
        acc3[i] = __builtin_amdgcn_mfma_f32_16x16x32_f16(a, b, acc3[i], 0,0,0);
      }
    }
    float* sres = (float*)(smem + OFF_RES);
    if (lr < 2){
      float bv = b3g[lr];
      #pragma unroll
      for (int i=0;i<3;i++) if (i < nm3){
        #pragma unroll
        for (int reg=0;reg<4;reg++){
          int m = m3t[i]*16 + lq*4 + reg;
          sres[lr*144 + m] = acc3[i][reg] + bv;
        }
      }
    }
  }
  __syncthreads();

  // ---- blend + outputs over 12x12 ----
  if (tid < 144){
    int ty = tid/12, tx = tid - ty*12;
    int gy = r0 + ty, gx = c0 + tx;
    if (gx < W_HI){
      const float* sres = (const float*)(smem + OFF_RES);
      float a0 = sres[tid], a1 = sres[144+tid];
      float alpha = fminf(fmaxf(a0, 0.0f), 1.0f);
      int pix = gy*W_HI + gx;
      const float* fp = FB + (size_t)n*4*HW_HI + pix;
      const float* hp = hbase + pix;
      float* op = histOut + (size_t)n*4*HW_HI + pix;
      float* rp = outp + (size_t)n*3*HW_HI + pix;
      #pragma unroll
      for (int c=0;c<4;c++){
        float h = hp[c*HW_HI]*(1.0f-alpha) + fp[c*HW_HI]*alpha;
        if (c == 3) h += a1;
        h = fminf(fmaxf(h, 0.0f), 1.0f);
        op[c*HW_HI] = h;
        if (c < 3) rp[c*HW_HI] = h;
      }
    }
  }
}

extern "C" void kernel_launch(void* const* d_in, const int* in_sizes, int n_in,
                              void* d_out, int out_size, void* d_ws, size_t ws_size,
                              hipStream_t stream){
  const float* frames = (const float*)d_in[0];
  const float* depths = (const float*)d_in[1];
  const float* mvs    = (const float*)d_in[2];
  const float* jits   = (const float*)d_in[3];
  const float* w1 = (const float*)d_in[4];
  const float* b1 = (const float*)d_in[5];
  const float* w2 = (const float*)d_in[6];
  const float* b2 = (const float*)d_in[7];
  const float* w3 = (const float*)d_in[8];
  const float* b3 = (const float*)d_in[9];
  float* out = (float*)d_out;

  float* FBp = (float*)d_ws;                       // [N,4,720,1280] f32
  float* HA  = FBp + (size_t)NB*4*HW_HI;           // history ping
  float* HB  = HA  + (size_t)NB*4*HW_HI;           // history pong
  f16*  wbuf = (f16*)(HB + (size_t)NB*4*HW_HI);    // 46592 f16 = 93184 B
  // total workspace: 88,473,600 + 93,184 B

  dim3 bs(256);
  int npix = NB*HW_HI;
  dim3 gpix((npix + 255)/256);
  dim3 gfused((W_HI + TILE-1)/TILE, (H_HI + TILE-1)/TILE, NB);

  k_wprep<<<dim3((46592+255)/256), bs, 0, stream>>>(w1, w2, w3, wbuf);

  for (int t = T_STEPS-1; t >= 0; --t){
    const float* fr = frames + (size_t)t*NB*3*HW_LO;
    const float* dp = depths + (size_t)t*NB*HW_LO;
    const float* mv = mvs    + (size_t)t*NB*HW_LO*2;
    const float* jt = jits   + (size_t)t*NB*2;
    float* ot = out + (size_t)t*NB*3*HW_HI;

    k_prep<<<gpix, bs, 0, stream>>>(fr, dp, jt, FBp);
    const float* histIn;
    if (t == T_STEPS-1) {
      histIn = FBp;
    } else {
      k_warp<<<gpix, bs, 0, stream>>>(HA, mv, FBp, HB);
      histIn = HB;
    }
    k_fused<<<gfused, bs, 0, stream>>>(fr, dp, jt, histIn, FBp, wbuf,
        b1, b2, b3, HA, ot);
  }
}

// Round 6
// 1692.362 us; speedup vs baseline: 11.2068x; 1.5073x over previous
//
#include <hip/hip_runtime.h>

#define T_STEPS 3
#define NB 2
#define H_LO 360
#define W_LO 640
#define H_HI 720
#define W_HI 1280
#define HW_LO (H_LO*W_LO)
#define HW_HI (H_HI*W_HI)
#define TILE 12

typedef _Float16 f16;
typedef __attribute__((ext_vector_type(8))) _Float16 f16x8;
typedef __attribute__((ext_vector_type(4))) float f32x4;

// LDS byte offsets (total 69504 <= 81920 for 2 blocks/CU)
#define OFF_W2  0              //  8192 B : w2 single buffer, one tap [64oc][64ic swz] f16
#define OFF_H1  8192           // 32768 B : h1 f16 [16][16][64 swz]
#define OFF_H2  40960          // 25088 B : h2 f16 [14][14][64 swz]
#define OFF_CNN OFF_H2         //  5184 B : cnn_in f16 [18][18][8] (alias, dead before h2 written)
#define OFF_W1  (OFF_H2+5184)  // 16384 B : w1 f16 [oc64][kk128 swz] (alias, dead before h2 written)
#define OFF_W3  66048          //  2304 B : w3 f16 [2][576]
#define OFF_RES 68352          //  1152 B : conv3 result f32 [2][144]
#define LDS_BYTES 69504

__device__ __forceinline__ int imin(int a,int b){return a<b?a:b;}
__device__ __forceinline__ int imax(int a,int b){return a>b?a:b;}
__device__ __forceinline__ int iclamp(int v,int lo,int hi){return imin(imax(v,lo),hi);}

__device__ __forceinline__ float depth_tx(float d0){
  float d = 10.0f / (100.0f - d0*99.9f);
  return (d - 0.1f) / 99.9f;
}

__device__ __forceinline__ void cubw(float t, float* w){
  const float a = -0.75f;
  float t2 = t*t, t3 = t2*t;
  w[0] = a*(t3 - 2.0f*t2 + t);
  w[1] = (a+2.0f)*t3 - (a+3.0f)*t2 + 1.0f;
  float s = 1.0f - t;
  w[2] = (a+2.0f)*s*s*s - (a+3.0f)*s*s + 1.0f;
  float u = 2.0f - t;
  w[3] = a*u*u*u - 5.0f*a*u*u + 8.0f*a*u - 4.0f*a;
}

// ---------------- FB4 = bicubic jitter-aligned upsample of [frame, depth_tx], interleaved float4 ----------------
__global__ __launch_bounds__(256) void k_prep(const float* __restrict__ frame,
    const float* __restrict__ depth, const float* __restrict__ jit,
    float4* __restrict__ FB){
  int idx = blockIdx.x*256 + threadIdx.x;
  if (idx >= NB*HW_HI) return;
  int n = idx / HW_HI, p = idx - n*HW_HI;
  int y = p / W_HI, x = p - y*W_HI;
  float jx = jit[n*2], jy = jit[n*2+1];
  float gx = (2.0f*(float)x + 1.0f)/(float)W_HI - 1.0f + 2.0f*(0.5f - jx)/(float)W_LO;
  float gy = (2.0f*(float)y + 1.0f)/(float)H_HI - 1.0f + 2.0f*(0.5f - jy)/(float)H_LO;
  float ix = ((gx + 1.0f)*(float)W_LO - 1.0f)*0.5f;
  float iy = ((gy + 1.0f)*(float)H_LO - 1.0f)*0.5f;
  float xf = floorf(ix), yf = floorf(iy);
  float tx = ix - xf, ty = iy - yf;
  int xi = (int)xf, yi = (int)yf;
  float wx[4], wy[4]; cubw(tx, wx); cubw(ty, wy);
  int xs[4], ys[4];
  #pragma unroll
  for (int j=0;j<4;j++){ xs[j]=iclamp(xi-1+j,0,W_LO-1); ys[j]=iclamp(yi-1+j,0,H_LO-1); }
  const float* fb = frame + (size_t)n*3*HW_LO;
  const float* db = depth + (size_t)n*HW_LO;
  float a0=0.f,a1=0.f,a2=0.f,a3=0.f;
  #pragma unroll
  for (int i=0;i<4;i++){
    #pragma unroll
    for (int j=0;j<4;j++){
      float wgt = wy[i]*wx[j];
      int off = ys[i]*W_LO + xs[j];
      a0 += wgt*fb[off];
      a1 += wgt*fb[HW_LO+off];
      a2 += wgt*fb[2*HW_LO+off];
      a3 += wgt*depth_tx(db[off]);
    }
  }
  FB[(size_t)n*HW_HI + p] = make_float4(a0,a1,a2,a3);
}

// ---------------- weight prep (EXACT R2 layout): f32 -> f16, relayout + XOR-swizzle ----------------
// wbuf f16: [0,8192) w1 [oc64][kk128]; [8192,45056) w2 [oc64][kk576]; [45056,46208) w3 [2][576]; pad to 46592
__global__ __launch_bounds__(256) void k_wprep(const float* __restrict__ w1g,
    const float* __restrict__ w2g, const float* __restrict__ w3g, f16* __restrict__ wbuf){
  int i = blockIdx.x*256 + threadIdx.x;
  if (i >= 46592) return;
  float val = 0.0f;
  if (i < 8192){
    int oc = i>>7, kk = i&127, k = kk ^ ((oc&7)<<3);      // k = tap*8+ic, pad [72,128)=0
    if (k < 72) val = w1g[(oc*8 + (k&7))*9 + (k>>3)];
  } else if (i < 45056){
    int j = i - 8192; int oc = j/576, kk = j - oc*576, k = kk ^ ((oc&7)<<3); // k = tap*64+ic
    val = w2g[(oc*64 + (k&63))*9 + (k>>6)];
  } else {
    int j = i - 45056;
    if (j < 1152){ int nn = j/576, k = j - nn*576;
      val = w3g[(nn*64 + (k&63))*9 + (k>>6)];
    }
  }
  wbuf[i] = (f16)val;
}

// ---------------- histB = bicubic warp of histA (interleaved float4) by bilinear mv; OOB -> FB4 copy ----------------
__global__ __launch_bounds__(256) void k_warp(const float4* __restrict__ histA,
    const float* __restrict__ mv, const float4* __restrict__ FB,
    float4* __restrict__ histB){
  int idx = blockIdx.x*256 + threadIdx.x;
  if (idx >= NB*HW_HI) return;
  int n = idx / HW_HI, p = idx - n*HW_HI;
  int y = p / W_HI, x = p - y*W_HI;
  float cy = fmaxf(((float)y + 0.5f)/2.0f - 0.5f, 0.0f);
  float cx = fmaxf(((float)x + 0.5f)/2.0f - 0.5f, 0.0f);
  float y0f = floorf(cy), x0f = floorf(cx);
  float tyv = cy - y0f, txv = cx - x0f;
  int y0 = iclamp((int)y0f, 0, H_LO-1), y1 = iclamp((int)y0f+1, 0, H_LO-1);
  int x0 = iclamp((int)x0f, 0, W_LO-1), x1 = iclamp((int)x0f+1, 0, W_LO-1);
  const float* mb = mv + (size_t)n*HW_LO*2;
  float gx, gy;
  {
    float v00 = mb[(y0*W_LO+x0)*2], v01 = mb[(y0*W_LO+x1)*2];
    float v10 = mb[(y1*W_LO+x0)*2], v11 = mb[(y1*W_LO+x1)*2];
    float r0 = v00*(1.0f-tyv) + v10*tyv;
    float r1 = v01*(1.0f-tyv) + v11*tyv;
    gx = r0*(1.0f-txv) + r1*txv;
  }
  {
    float v00 = mb[(y0*W_LO+x0)*2+1], v01 = mb[(y0*W_LO+x1)*2+1];
    float v10 = mb[(y1*W_LO+x0)*2+1], v11 = mb[(y1*W_LO+x1)*2+1];
    float r0 = v00*(1.0f-tyv) + v10*tyv;
    float r1 = v01*(1.0f-tyv) + v11*tyv;
    gy = r0*(1.0f-txv) + r1*txv;
  }
  bool oob = (gx > 1.0f) || (gx < -1.0f) || (gy > 1.0f) || (gy < -1.0f);
  float4 res;
  if (oob) {
    res = FB[(size_t)n*HW_HI + p];
  } else {
    const float4* hb = histA + (size_t)n*HW_HI;
    float ix = ((gx + 1.0f)*(float)W_HI - 1.0f)*0.5f;
    float iy = ((gy + 1.0f)*(float)H_HI - 1.0f)*0.5f;
    float xf = floorf(ix), yf = floorf(iy);
    float tx = ix - xf, ty = iy - yf;
    int xi = (int)xf, yi = (int)yf;
    float wx[4], wy[4]; cubw(tx, wx); cubw(ty, wy);
    int xs[4], ys[4];
    #pragma unroll
    for (int j=0;j<4;j++){ xs[j]=iclamp(xi-1+j,0,W_HI-1); ys[j]=iclamp(yi-1+j,0,H_HI-1); }
    float a0=0.f,a1=0.f,a2=0.f,a3=0.f;
    #pragma unroll
    for (int i=0;i<4;i++){
      #pragma unroll
      for (int j=0;j<4;j++){
        float wgt = wy[i]*wx[j];
        float4 v = hb[ys[i]*W_HI + xs[j]];
        a0 += wgt*v.x; a1 += wgt*v.y; a2 += wgt*v.z; a3 += wgt*v.w;
      }
    }
    res = make_float4(a0,a1,a2,a3);
  }
  histB[(size_t)n*HW_HI + p] = res;
}

// ---------------- fused conv1+conv2+conv3 (MFMA f16) + blend, 12x12 tile/block ----------------
__global__ __launch_bounds__(256,2) void k_fused(
    const float* __restrict__ frame, const float* __restrict__ depth,
    const float* __restrict__ jit, const float4* __restrict__ histIn,
    const float4* __restrict__ FB, const f16* __restrict__ wbuf,
    const float* __restrict__ b1g, const float* __restrict__ b2g, const float* __restrict__ b3g,
    float4* __restrict__ histOut, float* __restrict__ outp)
{
  __shared__ __attribute__((aligned(16))) char smem[LDS_BYTES];
  const int tid = threadIdx.x;
  const int wv = tid>>6, ln = tid&63, lr = ln&15, lq = ln>>4;
  const int n  = blockIdx.z;
  const int r0 = blockIdx.y * TILE;
  const int c0 = blockIdx.x * TILE;
  const float jx = jit[n*2], jy = jit[n*2+1];
  const int jix = (int)floorf(jx*2.0f), jiy = (int)floorf(jy*2.0f);
  const float* fbase = frame + (size_t)n*3*HW_LO;
  const float* dbase = depth + (size_t)n*HW_LO;
  const float4* hist4 = histIn + (size_t)n*HW_HI;

  // ---- Stage A: w1 + w3 staging, cnn_in tile (18x18x8) ----
  for (int i=tid; i<1024; i+=256) *(float4*)(smem+OFF_W1+i*16) = *(const float4*)((const char*)wbuf + i*16);
  const float4* w3src = (const float4*)(wbuf + 45056);
  for (int i=tid; i<144; i+=256) ((float4*)(smem + OFF_W3))[i] = w3src[i];

  for (int e=tid; e<324; e+=256){
    int u = e/18, v = e - u*18;
    int cgy = iclamp(r0-3+u, 0, H_HI-1);
    int cgx = iclamp(c0-3+v, 0, W_HI-1);
    float v0=0.f, v1=0.f, v2=0.f, v3=0.f;
    int yy = cgy - jiy, xx = cgx - jix;
    if (yy>=0 && xx>=0 && !(yy&1) && !(xx&1)){
      int off = (yy>>1)*W_LO + (xx>>1);
      v0 = fbase[off]; v1 = fbase[HW_LO+off]; v2 = fbase[2*HW_LO+off];
      v3 = depth_tx(dbase[off]);
    }
    float4 h = hist4[cgy*W_HI + cgx];
    f16x8 pk;
    pk[0]=(f16)v0; pk[1]=(f16)v1; pk[2]=(f16)v2; pk[3]=(f16)v3;
    pk[4]=(f16)h.x; pk[5]=(f16)h.y; pk[6]=(f16)h.z; pk[7]=(f16)h.w;
    *(f16x8*)(smem + OFF_CNN + e*16) = pk;
  }
  __syncthreads();

  // ---- conv1: M=256(16x16 halo grid), N=64, K=72(pad 96), k = tap*8+ic ----
  {
    f16x8 B1[3][4];
    #pragma unroll
    for (int kc=0;kc<3;kc++)
      #pragma unroll
      for (int oct=0;oct<4;oct++){
        int oc = oct*16 + lr;
        int k0 = kc*32 + lq*8;
        B1[kc][oct] = *(const f16x8*)(smem + OFF_W1 + ((oc*128 + (k0 ^ ((oc&7)<<3)))<<1));
      }
    float b1v[4];
    #pragma unroll
    for (int oct=0;oct<4;oct++) b1v[oct] = b1g[oct*16+lr];
    #pragma unroll
    for (int ty4=0;ty4<4;ty4++){
      int ty = wv*4 + ty4;
      int g1y = iclamp(r0-2+ty, 0, H_HI-1);
      int g1x = iclamp(c0-2+lr, 0, W_HI-1);
      f32x4 acc[4];
      #pragma unroll
      for (int oct=0;oct<4;oct++) acc[oct] = (f32x4){b1v[oct],b1v[oct],b1v[oct],b1v[oct]};
      #pragma unroll
      for (int kc=0;kc<3;kc++){
        int k0 = kc*32 + lq*8;
        int t = imin(k0>>3, 8);
        int dy = (t*11)>>5; int dx = t - dy*3;
        int uu = iclamp(g1y+dy-1, 0, H_HI-1) - (r0-3);
        int vv = iclamp(g1x+dx-1, 0, W_HI-1) - (c0-3);
        f16x8 a = *(const f16x8*)(smem + OFF_CNN + (uu*18+vv)*16);
        #pragma unroll
        for (int oct=0;oct<4;oct++)
          acc[oct] = __builtin_amdgcn_mfma_f32_16x16x32_f16(a, B1[kc][oct], acc[oct], 0,0,0);
      }
      #pragma unroll
      for (int oct=0;oct<4;oct++){
        int oc = oct*16 + lr;
        #pragma unroll
        for (int reg=0;reg<4;reg++){
          int tx = lq*4 + reg;
          *(f16*)(smem + OFF_H1 + (((ty*16+tx)*64 + (oc ^ ((tx&7)<<3)))<<1)) = (f16)fmaxf(acc[oct][reg], 0.f);
        }
      }
    }
  }
  __syncthreads();

  // ---- conv2: M=196(14x14, 13 tiles), N=64, K=576; w2 staged per tap, single buffer ----
  {
    const int nmt = (wv==0) ? 4 : 3;
    const int mtid[4] = {wv, 4+wv, 8+wv, 12};
    int rowOf[4][3], colc[4][3][2];
    #pragma unroll
    for (int mti=0;mti<4;mti++){
      int m = imin(mtid[mti]*16 + lr, 195);
      int py = m/14, px = m - py*14;
      int Ay = iclamp(r0-1+py, 0, H_HI-1);
      int Ax = iclamp(c0-1+px, 0, W_HI-1);
      #pragma unroll
      for (int d=0;d<3;d++){
        rowOf[mti][d] = (iclamp(Ay+d-1, 0, H_HI-1) - (r0-2))*1024;  // *16*64
        int vv = iclamp(Ax+d-1, 0, W_HI-1) - (c0-2);
        int key = (vv&7)<<3;
        colc[mti][d][0] = vv*64 + ((lq*8) ^ key);
        colc[mti][d][1] = vv*64 + ((32+lq*8) ^ key);
      }
    }
    float b2v[4];
    #pragma unroll
    for (int oct=0;oct<4;oct++) b2v[oct] = b2g[oct*16+lr];
    f32x4 acc2[4][4];
    #pragma unroll
    for (int mti=0;mti<4;mti++)
      #pragma unroll
      for (int oct=0;oct<4;oct++) acc2[mti][oct] = (f32x4){b2v[oct],b2v[oct],b2v[oct],b2v[oct]};
    int wb[4], wk[4];
    #pragma unroll
    for (int oct=0;oct<4;oct++){ int oc = oct*16+lr; wb[oct] = oc*64; wk[oct] = (oc&7)<<3; }
    const float4* w2src = (const float4*)(wbuf + 8192);   // [oc64][72 float4]
    for (int tap=0;tap<9;tap++){
      __syncthreads();   // prior tap's readers done before overwrite
      for (int i=tid;i<512;i+=256){
        int oc = i>>3, q = i&7;
        ((float4*)(smem + OFF_W2))[i] = w2src[oc*72 + tap*8 + q];
      }
      __syncthreads();   // staging visible
      const int dy = tap/3, dx = tap - dy*3;
      #pragma unroll
      for (int half=0; half<2; half++){
        int k0l = half*32 + lq*8;
        f16x8 bf[4];
        #pragma unroll
        for (int oct=0;oct<4;oct++)
          bf[oct] = *(const f16x8*)(smem + OFF_W2 + ((wb[oct] + (k0l ^ wk[oct]))<<1));
        #pragma unroll
        for (int mti=0;mti<4;mti++) if (mti < nmt){
          f16x8 a = *(const f16x8*)(smem + OFF_H1 + ((rowOf[mti][dy] + colc[mti][dx][half])<<1));
          #pragma unroll
          for (int oct=0;oct<4;oct++)
            acc2[mti][oct] = __builtin_amdgcn_mfma_f32_16x16x32_f16(a, bf[oct], acc2[mti][oct], 0,0,0);
        }
      }
    }
    __syncthreads();
    // write h2 (relu, swizzled)
    #pragma unroll
    for (int mti=0;mti<4;mti++) if (mti < nmt){
      #pragma unroll
      for (int reg=0;reg<4;reg++){
        int m = mtid[mti]*16 + lq*4 + reg;
        if (m < 196){
          int py = m/14, px = m - py*14;
          int base = (py*14+px)*64; int key = (px&7)<<3;
          #pragma unroll
          for (int oct=0;oct<4;oct++){
            int oc = oct*16 + lr;
            *(f16*)(smem + OFF_H2 + ((base + (oc ^ key))<<1)) = (f16)fmaxf(acc2[mti][oct][reg], 0.f);
          }
        }
      }
    }
  }
  __syncthreads();

  // ---- conv3: M=144(12x12, 9 tiles), N=2(pad 16), K=576 ----
  {
    const int nm3 = (wv==0) ? 3 : 2;
    const int m3t[3] = {wv, 4+wv, 8};
    int rowOf[3][3], colc[3][3][2];
    #pragma unroll
    for (int i=0;i<3;i++){
      int m = m3t[i]*16 + lr;           // < 144
      int py = m/12, px = m - py*12;
      int Cy = r0 + py;
      int Cx = iclamp(c0+px, 0, W_HI-1);
      #pragma unroll
      for (int d=0;d<3;d++){
        rowOf[i][d] = (iclamp(Cy+d-1, 0, H_HI-1) - (r0-1))*896;  // *14*64
        int vv = iclamp(Cx+d-1, 0, W_HI-1) - (c0-1);
        int key = (vv&7)<<3;
        colc[i][d][0] = vv*64 + ((lq*8) ^ key);
        colc[i][d][1] = vv*64 + ((32+lq*8) ^ key);
      }
    }
    f32x4 acc3[3] = {{0,0,0,0},{0,0,0,0},{0,0,0,0}};
    const int cidx = ln&1;
    #pragma unroll
    for (int kc=0;kc<18;kc++){
      const int tap = kc>>1, half = kc&1;
      const int dy = tap/3, dx = tap - dy*3;
      int k0 = kc*32 + lq*8;
      f16x8 b = *(const f16x8*)(smem + OFF_W3 + ((cidx*576 + k0)<<1));
      #pragma unroll
      for (int i=0;i<3;i++) if (i < nm3){
        f16x8 a = *(const f16x8*)(smem + OFF_H2 + ((rowOf[i][dy] + colc[i][dx][half])<<1));
        acc3[i] = __builtin_amdgcn_mfma_f32_16x16x32_f16(a, b, acc3[i], 0,0,0);
      }
    }
    float* sres = (float*)(smem + OFF_RES);
    if (lr < 2){
      float bv = b3g[lr];
      #pragma unroll
      for (int i=0;i<3;i++) if (i < nm3){
        #pragma unroll
        for (int reg=0;reg<4;reg++){
          int m = m3t[i]*16 + lq*4 + reg;
          sres[lr*144 + m] = acc3[i][reg] + bv;
        }
      }
    }
  }
  __syncthreads();

  // ---- blend + outputs over 12x12 ----
  if (tid < 144){
    int ty = tid/12, tx = tid - ty*12;
    int gy = r0 + ty, gx = c0 + tx;
    if (gx < W_HI){
      const float* sres = (const float*)(smem + OFF_RES);
      float a0 = sres[tid], a1 = sres[144+tid];
      float alpha = fminf(fmaxf(a0, 0.0f), 1.0f);
      int pix = gy*W_HI + gx;
      float4 fb = FB[(size_t)n*HW_HI + pix];
      float4 hv = hist4[pix];
      float h0 = hv.x*(1.0f-alpha) + fb.x*alpha;
      float h1 = hv.y*(1.0f-alpha) + fb.y*alpha;
      float h2 = hv.z*(1.0f-alpha) + fb.z*alpha;
      float h3 = hv.w*(1.0f-alpha) + fb.w*alpha + a1;
      h0 = fminf(fmaxf(h0,0.f),1.f); h1 = fminf(fmaxf(h1,0.f),1.f);
      h2 = fminf(fmaxf(h2,0.f),1.f); h3 = fminf(fmaxf(h3,0.f),1.f);
      histOut[(size_t)n*HW_HI + pix] = make_float4(h0,h1,h2,h3);
      float* rp = outp + (size_t)n*3*HW_HI + pix;
      rp[0] = h0; rp[HW_HI] = h1; rp[2*HW_HI] = h2;
    }
  }
}

extern "C" void kernel_launch(void* const* d_in, const int* in_sizes, int n_in,
                              void* d_out, int out_size, void* d_ws, size_t ws_size,
                              hipStream_t stream){
  const float* frames = (const float*)d_in[0];
  const float* depths = (const float*)d_in[1];
  const float* mvs    = (const float*)d_in[2];
  const float* jits   = (const float*)d_in[3];
  const float* w1 = (const float*)d_in[4];
  const float* b1 = (const float*)d_in[5];
  const float* w2 = (const float*)d_in[6];
  const float* b2 = (const float*)d_in[7];
  const float* w3 = (const float*)d_in[8];
  const float* b3 = (const float*)d_in[9];
  float* out = (float*)d_out;

  float4* FB4 = (float4*)d_ws;                     // [N][HW][4] f32 interleaved
  float4* HA  = FB4 + (size_t)NB*HW_HI;            // history ping
  float4* HB  = HA  + (size_t)NB*HW_HI;            // history pong
  f16*  wbuf = (f16*)(HB + (size_t)NB*HW_HI);      // 46592 f16 = 93184 B
  // total workspace: 88,473,600 + 93,184 B

  dim3 bs(256);
  int npix = NB*HW_HI;
  dim3 gpix((npix + 255)/256);
  dim3 gfused((W_HI + TILE-1)/TILE, (H_HI + TILE-1)/TILE, NB);

  k_wprep<<<dim3((46592+255)/256), bs, 0, stream>>>(w1, w2, w3, wbuf);

  for (int t = T_STEPS-1; t >= 0; --t){
    const float* fr = frames + (size_t)t*NB*3*HW_LO;
    const float* dp = depths + (size_t)t*NB*HW_LO;
    const float* mv = mvs    + (size_t)t*NB*HW_LO*2;
    const float* jt = jits   + (size_t)t*NB*2;
    float* ot = out + (size_t)t*NB*3*HW_HI;

    k_prep<<<gpix, bs, 0, stream>>>(fr, dp, jt, FB4);
    const float4* histIn;
    if (t == T_STEPS-1) {
      histIn = FB4;
    } else {
      k_warp<<<gpix, bs, 0, stream>>>(HA, mv, FB4, HB);
      histIn = HB;
    }
    k_fused<<<gfused, bs, 0, stream>>>(fr, dp, jt, histIn, FB4, wbuf,
        b1, b2, b3, HA, ot);
  }
}

// Round 7
// 1625.880 us; speedup vs baseline: 11.6650x; 1.0409x over previous
//
#include <hip/hip_runtime.h>

#define T_STEPS 3
#define NB 2
#define H_LO 360
#define W_LO 640
#define H_HI 720
#define W_HI 1280
#define HW_LO (H_LO*W_LO)
#define HW_HI (H_HI*W_HI)
#define TILE 12

typedef _Float16 f16;
typedef __attribute__((ext_vector_type(4))) _Float16 f16x4;
typedef __attribute__((ext_vector_type(8))) _Float16 f16x8;
typedef __attribute__((ext_vector_type(4))) float f32x4;

// LDS byte offsets (total 59008 -> 2 blocks/CU)
#define OFF_H1  0              // 32768 B : h1 f16 [16][16][64 swz]
#define OFF_H2  32768          // 25088 B : h2 f16 [14][14][64 swz]
#define OFF_CNN OFF_H2         //  5184 B : cnn_in f16 [18][18][8] (alias, dead before h2 written)
#define OFF_RES 57856          //  1152 B : conv3 result f32 [2][144]
#define LDS_BYTES 59008

__device__ __forceinline__ int imin(int a,int b){return a<b?a:b;}
__device__ __forceinline__ int imax(int a,int b){return a>b?a:b;}
__device__ __forceinline__ int iclamp(int v,int lo,int hi){return imin(imax(v,lo),hi);}

__device__ __forceinline__ float depth_tx(float d0){
  float d = 10.0f / (100.0f - d0*99.9f);
  return (d - 0.1f) / 99.9f;
}

__device__ __forceinline__ void cubw(float t, float* w){
  const float a = -0.75f;
  float t2 = t*t, t3 = t2*t;
  w[0] = a*(t3 - 2.0f*t2 + t);
  w[1] = (a+2.0f)*t3 - (a+3.0f)*t2 + 1.0f;
  float s = 1.0f - t;
  w[2] = (a+2.0f)*s*s*s - (a+3.0f)*s*s + 1.0f;
  float u = 2.0f - t;
  w[3] = a*u*u*u - 5.0f*a*u*u + 8.0f*a*u - 4.0f*a;
}

// ---------------- FB4 = bicubic jitter-aligned upsample of [frame, depth_tx], interleaved float4 ----------------
__global__ __launch_bounds__(256) void k_prep(const float* __restrict__ frame,
    const float* __restrict__ depth, const float* __restrict__ jit,
    float4* __restrict__ FB){
  int idx = blockIdx.x*256 + threadIdx.x;
  if (idx >= NB*HW_HI) return;
  int n = idx / HW_HI, p = idx - n*HW_HI;
  int y = p / W_HI, x = p - y*W_HI;
  float jx = jit[n*2], jy = jit[n*2+1];
  float gx = (2.0f*(float)x + 1.0f)/(float)W_HI - 1.0f + 2.0f*(0.5f - jx)/(float)W_LO;
  float gy = (2.0f*(float)y + 1.0f)/(float)H_HI - 1.0f + 2.0f*(0.5f - jy)/(float)H_LO;
  float ix = ((gx + 1.0f)*(float)W_LO - 1.0f)*0.5f;
  float iy = ((gy + 1.0f)*(float)H_LO - 1.0f)*0.5f;
  float xf = floorf(ix), yf = floorf(iy);
  float tx = ix - xf, ty = iy - yf;
  int xi = (int)xf, yi = (int)yf;
  float wx[4], wy[4]; cubw(tx, wx); cubw(ty, wy);
  int xs[4], ys[4];
  #pragma unroll
  for (int j=0;j<4;j++){ xs[j]=iclamp(xi-1+j,0,W_LO-1); ys[j]=iclamp(yi-1+j,0,H_LO-1); }
  const float* fb = frame + (size_t)n*3*HW_LO;
  const float* db = depth + (size_t)n*HW_LO;
  float a0=0.f,a1=0.f,a2=0.f,a3=0.f;
  #pragma unroll
  for (int i=0;i<4;i++){
    #pragma unroll
    for (int j=0;j<4;j++){
      float wgt = wy[i]*wx[j];
      int off = ys[i]*W_LO + xs[j];
      a0 += wgt*fb[off];
      a1 += wgt*fb[HW_LO+off];
      a2 += wgt*fb[2*HW_LO+off];
      a3 += wgt*depth_tx(db[off]);
    }
  }
  FB[(size_t)n*HW_HI + p] = make_float4(a0,a1,a2,a3);
}

// ---------------- weight prep (EXACT R2 layout): f32 -> f16, relayout + XOR-swizzle ----------------
// wbuf f16: [0,8192) w1 [oc64][kk128]; [8192,45056) w2 [oc64][kk576]; [45056,46208) w3 [2][576]; pad to 46592
__global__ __launch_bounds__(256) void k_wprep(const float* __restrict__ w1g,
    const float* __restrict__ w2g, const float* __restrict__ w3g, f16* __restrict__ wbuf){
  int i = blockIdx.x*256 + threadIdx.x;
  if (i >= 46592) return;
  float val = 0.0f;
  if (i < 8192){
    int oc = i>>7, kk = i&127, k = kk ^ ((oc&7)<<3);      // k = tap*8+ic, pad [72,128)=0
    if (k < 72) val = w1g[(oc*8 + (k&7))*9 + (k>>3)];
  } else if (i < 45056){
    int j = i - 8192; int oc = j/576, kk = j - oc*576, k = kk ^ ((oc&7)<<3); // k = tap*64+ic
    val = w2g[(oc*64 + (k&63))*9 + (k>>6)];
  } else {
    int j = i - 45056;
    if (j < 1152){ int nn = j/576, k = j - nn*576;
      val = w3g[(nn*64 + (k&63))*9 + (k>>6)];
    }
  }
  wbuf[i] = (f16)val;
}

// ---------------- histB = bicubic warp of histA (interleaved float4) by bilinear mv; OOB -> FB4 copy ----------------
__global__ __launch_bounds__(256) void k_warp(const float4* __restrict__ histA,
    const float* __restrict__ mv, const float4* __restrict__ FB,
    float4* __restrict__ histB){
  int idx = blockIdx.x*256 + threadIdx.x;
  if (idx >= NB*HW_HI) return;
  int n = idx / HW_HI, p = idx - n*HW_HI;
  int y = p / W_HI, x = p - y*W_HI;
  float cy = fmaxf(((float)y + 0.5f)/2.0f - 0.5f, 0.0f);
  float cx = fmaxf(((float)x + 0.5f)/2.0f - 0.5f, 0.0f);
  float y0f = floorf(cy), x0f = floorf(cx);
  float tyv = cy - y0f, txv = cx - x0f;
  int y0 = iclamp((int)y0f, 0, H_LO-1), y1 = iclamp((int)y0f+1, 0, H_LO-1);
  int x0 = iclamp((int)x0f, 0, W_LO-1), x1 = iclamp((int)x0f+1, 0, W_LO-1);
  const float* mb = mv + (size_t)n*HW_LO*2;
  float gx, gy;
  {
    float v00 = mb[(y0*W_LO+x0)*2], v01 = mb[(y0*W_LO+x1)*2];
    float v10 = mb[(y1*W_LO+x0)*2], v11 = mb[(y1*W_LO+x1)*2];
    float r0 = v00*(1.0f-tyv) + v10*tyv;
    float r1 = v01*(1.0f-tyv) + v11*tyv;
    gx = r0*(1.0f-txv) + r1*txv;
  }
  {
    float v00 = mb[(y0*W_LO+x0)*2+1], v01 = mb[(y0*W_LO+x1)*2+1];
    float v10 = mb[(y1*W_LO+x0)*2+1], v11 = mb[(y1*W_LO+x1)*2+1];
    float r0 = v00*(1.0f-tyv) + v10*tyv;
    float r1 = v01*(1.0f-tyv) + v11*tyv;
    gy = r0*(1.0f-txv) + r1*txv;
  }
  bool oob = (gx > 1.0f) || (gx < -1.0f) || (gy > 1.0f) || (gy < -1.0f);
  float4 res;
  if (oob) {
    res = FB[(size_t)n*HW_HI + p];
  } else {
    const float4* hb = histA + (size_t)n*HW_HI;
    float ix = ((gx + 1.0f)*(float)W_HI - 1.0f)*0.5f;
    float iy = ((gy + 1.0f)*(float)H_HI - 1.0f)*0.5f;
    float xf = floorf(ix), yf = floorf(iy);
    float tx = ix - xf, ty = iy - yf;
    int xi = (int)xf, yi = (int)yf;
    float wx[4], wy[4]; cubw(tx, wx); cubw(ty, wy);
    int xs[4], ys[4];
    #pragma unroll
    for (int j=0;j<4;j++){ xs[j]=iclamp(xi-1+j,0,W_HI-1); ys[j]=iclamp(yi-1+j,0,H_HI-1); }
    float a0=0.f,a1=0.f,a2=0.f,a3=0.f;
    #pragma unroll
    for (int i=0;i<4;i++){
      #pragma unroll
      for (int j=0;j<4;j++){
        float wgt = wy[i]*wx[j];
        float4 v = hb[ys[i]*W_HI + xs[j]];
        a0 += wgt*v.x; a1 += wgt*v.y; a2 += wgt*v.z; a3 += wgt*v.w;
      }
    }
    res = make_float4(a0,a1,a2,a3);
  }
  histB[(size_t)n*HW_HI + p] = res;
}

// ---------------- fused conv1+conv2+conv3 (MFMA f16, weights from L2) + blend, 12x12 tile/block ----------------
__global__ __launch_bounds__(256,2) void k_fused(
    const float* __restrict__ frame, const float* __restrict__ depth,
    const float* __restrict__ jit, const float4* __restrict__ histIn,
    const float4* __restrict__ FB, const f16* __restrict__ wbuf,
    const float* __restrict__ b1g, const float* __restrict__ b2g, const float* __restrict__ b3g,
    float4* __restrict__ histOut, float* __restrict__ outp)
{
  __shared__ __attribute__((aligned(16))) char smem[LDS_BYTES];
  const int tid = threadIdx.x;
  const int wv = tid>>6, ln = tid&63, lr = ln&15, lq = ln>>4;
  const int n  = blockIdx.z;
  const int r0 = blockIdx.y * TILE;
  const int c0 = blockIdx.x * TILE;
  const float jx = jit[n*2], jy = jit[n*2+1];
  const int jix = (int)floorf(jx*2.0f), jiy = (int)floorf(jy*2.0f);
  const float* fbase = frame + (size_t)n*3*HW_LO;
  const float* dbase = depth + (size_t)n*HW_LO;
  const float4* hist4 = histIn + (size_t)n*HW_HI;
  const int wkk = (lr&7)<<3;     // weight k-swizzle key (oc&7 == lr&7)

  // prefetch conv1 A-fragments (weights) from global before LDS staging (latency hides under stage A)
  f16x8 B1[3][4];
  #pragma unroll
  for (int kc=0;kc<3;kc++)
    #pragma unroll
    for (int oct=0;oct<4;oct++){
      int oc = oct*16 + lr;
      int k0 = kc*32 + lq*8;
      B1[kc][oct] = *(const f16x8*)(wbuf + oc*128 + (k0 ^ wkk));
    }

  // ---- Stage A: cnn_in tile (18x18x8) ----
  for (int e=tid; e<324; e+=256){
    int u = e/18, v = e - u*18;
    int cgy = iclamp(r0-3+u, 0, H_HI-1);
    int cgx = iclamp(c0-3+v, 0, W_HI-1);
    float v0=0.f, v1=0.f, v2=0.f, v3=0.f;
    int yy = cgy - jiy, xx = cgx - jix;
    if (yy>=0 && xx>=0 && !(yy&1) && !(xx&1)){
      int off = (yy>>1)*W_LO + (xx>>1);
      v0 = fbase[off]; v1 = fbase[HW_LO+off]; v2 = fbase[2*HW_LO+off];
      v3 = depth_tx(dbase[off]);
    }
    float4 h = hist4[cgy*W_HI + cgx];
    f16x8 pk;
    pk[0]=(f16)v0; pk[1]=(f16)v1; pk[2]=(f16)v2; pk[3]=(f16)v3;
    pk[4]=(f16)h.x; pk[5]=(f16)h.y; pk[6]=(f16)h.z; pk[7]=(f16)h.w;
    *(f16x8*)(smem + OFF_CNN + e*16) = pk;
  }
  __syncthreads();

  // ---- conv1: D[oc][px] (weights as A-operand), M=oc 64, N=16 px/row, K=96 ----
  {
    float4 b1v[4];
    #pragma unroll
    for (int oct=0;oct<4;oct++) b1v[oct] = *(const float4*)(b1g + oct*16 + lq*4);
    #pragma unroll
    for (int ty4=0;ty4<4;ty4++){
      int ty = wv*4 + ty4;
      int g1y = iclamp(r0-2+ty, 0, H_HI-1);
      int g1x = iclamp(c0-2+lr, 0, W_HI-1);
      f32x4 acc[4];
      #pragma unroll
      for (int oct=0;oct<4;oct++) acc[oct] = (f32x4){b1v[oct].x,b1v[oct].y,b1v[oct].z,b1v[oct].w};
      #pragma unroll
      for (int kc=0;kc<3;kc++){
        int k0 = kc*32 + lq*8;
        int t = imin(k0>>3, 8);
        int dy = (t*11)>>5; int dx = t - dy*3;
        int uu = iclamp(g1y+dy-1, 0, H_HI-1) - (r0-3);
        int vv = iclamp(g1x+dx-1, 0, W_HI-1) - (c0-3);
        f16x8 a = *(const f16x8*)(smem + OFF_CNN + (uu*18+vv)*16);
        #pragma unroll
        for (int oct=0;oct<4;oct++)
          acc[oct] = __builtin_amdgcn_mfma_f32_16x16x32_f16(B1[kc][oct], a, acc[oct], 0,0,0);
      }
      // h1 write: lane's pixel = lr, oc = oct*16 + lq*4 + reg  ->  one f16x4 per oct
      #pragma unroll
      for (int oct=0;oct<4;oct++){
        f16x4 wv4;
        #pragma unroll
        for (int reg=0;reg<4;reg++) wv4[reg] = (f16)fmaxf(acc[oct][reg], 0.f);
        int oc0 = (oct*16 + lq*4) ^ ((lr&7)<<3);
        *(f16x4*)(smem + OFF_H1 + (((ty*16+lr)*64 + oc0)<<1)) = wv4;
      }
    }
  }
  __syncthreads();

  // ---- conv2: D[oc][m] (weights as A-operand), M=oc 64, N=196 px (13 tiles), K=576; w2 from L2 ----
  {
    const int nmt = (wv==0) ? 4 : 3;
    const int mtid[4] = {wv, 4+wv, 8+wv, 12};
    int rowOf[4][3], colc[4][3][2];
    #pragma unroll
    for (int mti=0;mti<4;mti++){
      int m = imin(mtid[mti]*16 + lr, 195);
      int py = m/14, px = m - py*14;
      int Ay = iclamp(r0-1+py, 0, H_HI-1);
      int Ax = iclamp(c0-1+px, 0, W_HI-1);
      #pragma unroll
      for (int d=0;d<3;d++){
        rowOf[mti][d] = (iclamp(Ay+d-1, 0, H_HI-1) - (r0-2))*1024;  // *16*64
        int vv = iclamp(Ax+d-1, 0, W_HI-1) - (c0-2);
        int key = (vv&7)<<3;
        colc[mti][d][0] = vv*64 + ((lq*8) ^ key);
        colc[mti][d][1] = vv*64 + ((32+lq*8) ^ key);
      }
    }
    float4 b2v[4];
    #pragma unroll
    for (int oct=0;oct<4;oct++) b2v[oct] = *(const float4*)(b2g + oct*16 + lq*4);
    f32x4 acc2[4][4];
    #pragma unroll
    for (int mti=0;mti<4;mti++)
      #pragma unroll
      for (int oct=0;oct<4;oct++) acc2[mti][oct] = (f32x4){b2v[oct].x,b2v[oct].y,b2v[oct].z,b2v[oct].w};
    const f16* w2b = wbuf + 8192;   // [oc64][k576 swz]
    for (int tap=0;tap<9;tap++){
      const int dy = tap/3, dx = tap - dy*3;
      #pragma unroll
      for (int half=0; half<2; half++){
        f16x8 bf[4];
        #pragma unroll
        for (int oct=0;oct<4;oct++){
          int oc = oct*16 + lr;
          bf[oct] = *(const f16x8*)(w2b + oc*576 + ((tap*64 + half*32 + lq*8) ^ wkk));
        }
        #pragma unroll
        for (int mti=0;mti<4;mti++) if (mti < nmt){
          f16x8 a = *(const f16x8*)(smem + OFF_H1 + ((rowOf[mti][dy] + colc[mti][dx][half])<<1));
          #pragma unroll
          for (int oct=0;oct<4;oct++)
            acc2[mti][oct] = __builtin_amdgcn_mfma_f32_16x16x32_f16(bf[oct], a, acc2[mti][oct], 0,0,0);
        }
      }
    }
    // h2 write (relu, swizzled): lane's m = mtid*16+lr, oc = oct*16+lq*4+reg -> f16x4 stores
    #pragma unroll
    for (int mti=0;mti<4;mti++) if (mti < nmt){
      int m = mtid[mti]*16 + lr;
      if (m < 196){
        int py = m/14, px = m - py*14;
        int base = (py*14+px)*64; int key = (px&7)<<3;
        #pragma unroll
        for (int oct=0;oct<4;oct++){
          f16x4 wv4;
          #pragma unroll
          for (int reg=0;reg<4;reg++) wv4[reg] = (f16)fmaxf(acc2[mti][oct][reg], 0.f);
          *(f16x4*)(smem + OFF_H2 + ((base + ((oct*16 + lq*4) ^ key))<<1)) = wv4;
        }
      }
    }
  }
  __syncthreads();

  // ---- conv3: M=144(12x12, 9 tiles), N=2(pad 16), K=576; w3 from L2 ----
  {
    const int nm3 = (wv==0) ? 3 : 2;
    const int m3t[3] = {wv, 4+wv, 8};
    int rowOf[3][3], colc[3][3][2];
    #pragma unroll
    for (int i=0;i<3;i++){
      int m = m3t[i]*16 + lr;           // < 144
      int py = m/12, px = m - py*12;
      int Cy = r0 + py;
      int Cx = iclamp(c0+px, 0, W_HI-1);
      #pragma unroll
      for (int d=0;d<3;d++){
        rowOf[i][d] = (iclamp(Cy+d-1, 0, H_HI-1) - (r0-1))*896;  // *14*64
        int vv = iclamp(Cx+d-1, 0, W_HI-1) - (c0-1);
        int key = (vv&7)<<3;
        colc[i][d][0] = vv*64 + ((lq*8) ^ key);
        colc[i][d][1] = vv*64 + ((32+lq*8) ^ key);
      }
    }
    f32x4 acc3[3] = {{0,0,0,0},{0,0,0,0},{0,0,0,0}};
    const int cidx = ln&1;
    const f16* w3b = wbuf + 45056;
    #pragma unroll
    for (int kc=0;kc<18;kc++){
      const int tap = kc>>1, half = kc&1;
      const int dy = tap/3, dx = tap - dy*3;
      int k0 = kc*32 + lq*8;
      f16x8 b = *(const f16x8*)(w3b + cidx*576 + k0);
      #pragma unroll
      for (int i=0;i<3;i++) if (i < nm3){
        f16x8 a = *(const f16x8*)(smem + OFF_H2 + ((rowOf[i][dy] + colc[i][dx][half])<<1));
        acc3[i] = __builtin_amdgcn_mfma_f32_16x16x32_f16(a, b, acc3[i], 0,0,0);
      }
    }
    float* sres = (float*)(smem + OFF_RES);
    if (lr < 2){
      float bv = b3g[lr];
      #pragma unroll
      for (int i=0;i<3;i++) if (i < nm3){
        #pragma unroll
        for (int reg=0;reg<4;reg++){
          int m = m3t[i]*16 + lq*4 + reg;
          sres[lr*144 + m] = acc3[i][reg] + bv;
        }
      }
    }
  }
  __syncthreads();

  // ---- blend + outputs over 12x12 ----
  if (tid < 144){
    int ty = tid/12, tx = tid - ty*12;
    int gy = r0 + ty, gx = c0 + tx;
    if (gx < W_HI){
      const float* sres = (const float*)(smem + OFF_RES);
      float a0 = sres[tid], a1 = sres[144+tid];
      float alpha = fminf(fmaxf(a0, 0.0f), 1.0f);
      int pix = gy*W_HI + gx;
      float4 fb = FB[(size_t)n*HW_HI + pix];
      float4 hv = hist4[pix];
      float h0 = hv.x*(1.0f-alpha) + fb.x*alpha;
      float h1 = hv.y*(1.0f-alpha) + fb.y*alpha;
      float h2 = hv.z*(1.0f-alpha) + fb.z*alpha;
      float h3 = hv.w*(1.0f-alpha) + fb.w*alpha + a1;
      h0 = fminf(fmaxf(h0,0.f),1.f); h1 = fminf(fmaxf(h1,0.f),1.f);
      h2 = fminf(fmaxf(h2,0.f),1.f); h3 = fminf(fmaxf(h3,0.f),1.f);
      histOut[(size_t)n*HW_HI + pix] = make_float4(h0,h1,h2,h3);
      float* rp = outp + (size_t)n*3*HW_HI + pix;
      rp[0] = h0; rp[HW_HI] = h1; rp[2*HW_HI] = h2;
    }
  }
}

extern "C" void kernel_launch(void* const* d_in, const int* in_sizes, int n_in,
                              void* d_out, int out_size, void* d_ws, size_t ws_size,
                              hipStream_t stream){
  const float* frames = (const float*)d_in[0];
  const float* depths = (const float*)d_in[1];
  const float* mvs    = (const float*)d_in[2];
  const float* jits   = (const float*)d_in[3];
  const float* w1 = (const float*)d_in[4];
  const float* b1 = (const float*)d_in[5];
  const float* w2 = (const float*)d_in[6];
  const float* b2 = (const float*)d_in[7];
  const float* w3 = (const float*)d_in[8];
  const float* b3 = (const float*)d_in[9];
  float* out = (float*)d_out;

  float4* FB4 = (float4*)d_ws;                     // [N][HW][4] f32 interleaved
  float4* HA  = FB4 + (size_t)NB*HW_HI;            // history ping
  float4* HB  = HA  + (size_t)NB*HW_HI;            // history pong
  f16*  wbuf = (f16*)(HB + (size_t)NB*HW_HI);      // 46592 f16 = 93184 B
  // total workspace: 88,473,600 + 93,184 B

  dim3 bs(256);
  int npix = NB*HW_HI;
  dim3 gpix((npix + 255)/256);
  dim3 gfused((W_HI + TILE-1)/TILE, (H_HI + TILE-1)/TILE, NB);

  k_wprep<<<dim3((46592+255)/256), bs, 0, stream>>>(w1, w2, w3, wbuf);

  for (int t = T_STEPS-1; t >= 0; --t){
    const float* fr = frames + (size_t)t*NB*3*HW_LO;
    const float* dp = depths + (size_t)t*NB*HW_LO;
    const float* mv = mvs    + (size_t)t*NB*HW_LO*2;
    const float* jt = jits   + (size_t)t*NB*2;
    float* ot = out + (size_t)t*NB*3*HW_HI;

    k_prep<<<gpix, bs, 0, stream>>>(fr, dp, jt, FB4);
    const float4* histIn;
    if (t == T_STEPS-1) {
      histIn = FB4;
    } else {
      k_warp<<<gpix, bs, 0, stream>>>(HA, mv, FB4, HB);
      histIn = HB;
    }
    k_fused<<<gfused, bs, 0, stream>>>(fr, dp, jt, histIn, FB4, wbuf,
        b1, b2, b3, HA, ot);
  }
}